// Round 5
// baseline (1422.890 us; speedup 1.0000x reference)
//
#include <hip/hip_runtime.h>
#include <hip/hip_bf16.h>
#include <cmath>

#define N_ATOMS 20000
#define NE      320000
#define FDIM    64
#define NRBF    32
#define PI_F    3.14159265358979323846f

typedef __attribute__((ext_vector_type(8))) short bf16x8;
typedef __attribute__((ext_vector_type(4))) float f32x4;

#define MFMA16(a, b, c) __builtin_amdgcn_mfma_f32_16x16x32_bf16(a, b, c, 0, 0, 0)

__device__ __forceinline__ float silu(float x) {
    return x / (1.0f + __expf(-x));
}

__device__ __forceinline__ unsigned short f2bf_rne(float x) {
    unsigned u = __float_as_uint(x);
    u += 0x7fffu + ((u >> 16) & 1u);
    return (unsigned short)(u >> 16);
}

__device__ __forceinline__ float bf2f(unsigned short us) {
    return __uint_as_float((unsigned)us << 16);
}

// split fp32 -> hi (truncated bf16) + lo (RNE bf16 of residual); hi+lo ~ 2^-17 rel
__device__ __forceinline__ void split8(const float* v, bf16x8& hi, bf16x8& lo) {
#pragma unroll
    for (int j = 0; j < 8; j++) {
        unsigned u = __float_as_uint(v[j]);
        float hf = __uint_as_float(u & 0xffff0000u);
        hi[j] = (short)(u >> 16);
        lo[j] = (short)f2bf_rne(v[j] - hf);
    }
}

// ---------------- transpose wtT[k][f][g] from Wt[k][g][f] ----------------
__global__ void transpose_kernel(const float* __restrict__ Wt, float* __restrict__ wtT) {
    int idx = blockIdx.x * 256 + threadIdx.x;
    if (idx >= 24576) return;
    int k = idx >> 12;
    int r = idx & 4095;
    int g = r >> 6;
    int f = r & 63;
    wtT[k * 4096 + f * 64 + g] = Wt[idx];
}

// ---------------- weight fragment prep: hi/lo bf16 planes, MFMA B-layout ----------------
// frag index t = ((ks*NT + nt)*64 + lane)*8 + j ; element = W[n*K + k],
// n = nt*16 + (lane&15), k = ks*32 + (lane>>4)*8 + j.
__global__ void wfrag_kernel(const float* __restrict__ W0, const float* __restrict__ W1,
                             const float* __restrict__ W2,
                             unsigned short* __restrict__ f0h, unsigned short* __restrict__ f0l,
                             unsigned short* __restrict__ f1h, unsigned short* __restrict__ f1l,
                             unsigned short* __restrict__ f2h, unsigned short* __restrict__ f2l) {
    int idx = blockIdx.x * 256 + threadIdx.x;
    const float* W;
    unsigned short *fh, *fl;
    int t, K, NT;
    if (idx < 2048)       { W = W0; fh = f0h; fl = f0l; t = idx;         K = 32;  NT = 4; }
    else if (idx < 10240) { W = W1; fh = f1h; fl = f1l; t = idx - 2048;  K = 64;  NT = 8; }
    else if (idx < 34816) { W = W2; fh = f2h; fl = f2l; t = idx - 10240; K = 128; NT = 12; }
    else return;
    int j = t & 7;
    int lane = (t >> 3) & 63;
    int rest = t >> 9;
    int nt = rest % NT;
    int ks = rest / NT;
    int k = ks * 32 + ((lane >> 4) & 3) * 8 + j;
    int n = nt * 16 + (lane & 15);
    float w = W[n * K + k];
    unsigned u = __float_as_uint(w);
    float hf = __uint_as_float(u & 0xffff0000u);
    fh[t] = (unsigned short)(u >> 16);
    fl[t] = f2bf_rne(w - hf);
}

// ---------------- CSR build ----------------
__global__ void hist_kernel(const int* __restrict__ dst, int* __restrict__ deg) {
    int e = blockIdx.x * 256 + threadIdx.x;
    if (e >= NE) return;
    atomicAdd(&deg[dst[e]], 1);
}

__global__ void scan_kernel(const int* __restrict__ deg, int* __restrict__ off) {
    __shared__ int part[1024];
    int t = threadIdx.x;
    const int CH = (N_ATOMS + 1023) / 1024; // 20
    int base = t * CH;
    int s = 0;
    for (int i = 0; i < CH; i++) {
        int idx = base + i;
        if (idx < N_ATOMS) s += deg[idx];
    }
    part[t] = s;
    __syncthreads();
    for (int ofs = 1; ofs < 1024; ofs <<= 1) {
        int v = (t >= ofs) ? part[t - ofs] : 0;
        __syncthreads();
        part[t] += v;
        __syncthreads();
    }
    int run = (t == 0) ? 0 : part[t - 1];
    for (int i = 0; i < CH; i++) {
        int idx = base + i;
        if (idx < N_ATOMS) {
            off[idx] = run;
            run += deg[idx];
        }
    }
    if (t == 1023) off[N_ATOMS] = run;
}

// ebkt[slot] = edge id, sbkt[slot] = src atom; slots CSR-ordered by dst.
__global__ void fill_kernel(const int* __restrict__ dst, const int* __restrict__ srcArr,
                            const int* __restrict__ off, int* __restrict__ cursor,
                            int* __restrict__ ebkt, int* __restrict__ sbkt) {
    int e = blockIdx.x * 256 + threadIdx.x;
    if (e >= NE) return;
    int d = dst[e];
    int pos = atomicAdd(&cursor[d], 1);
    int slot = off[d] + pos;
    ebkt[slot] = e;
    sbkt[slot] = srcArr[e];
}

// ---------------- fused decompose + lin1 ----------------
// comp rows padded 10 -> 12 floats (48 B, 16B-aligned): gather uses 3x float4.
__global__ __launch_bounds__(256) void lin1_kernel(
    const float* __restrict__ X, const float* __restrict__ wtT,
    float* __restrict__ comp, float* __restrict__ Yb) {
    __shared__ float lds[4][64 * 11];
    int w = threadIdx.x >> 6;
    int l = threadIdx.x & 63;
    int a = blockIdx.x * 4 + w;

    {
        const float* x = X + ((size_t)a * 64 + l) * 9;
        float v[9];
#pragma unroll
        for (int i = 0; i < 9; i++) v[i] = x[i];
        float t2 = 0.f;
#pragma unroll
        for (int i = 0; i < 9; i++) t2 += v[i] * v[i];
        float inv = 1.0f / (t2 + 1.0f);
#pragma unroll
        for (int i = 0; i < 9; i++) v[i] *= inv;
        float iso = (v[0] + v[4] + v[8]) * (1.0f / 3.0f);
        float* o = &lds[w][l * 11];
        o[0] = iso;
        o[1] = 0.5f * (v[1] - v[3]);
        o[2] = 0.5f * (v[2] - v[6]);
        o[3] = 0.5f * (v[5] - v[7]);
        o[4] = v[0] - iso;
        o[5] = 0.5f * (v[1] + v[3]);
        o[6] = 0.5f * (v[2] + v[6]);
        o[7] = v[4] - iso;
        o[8] = 0.5f * (v[5] + v[7]);
        o[9] = v[8] - iso;
    }
    __syncthreads();
    {
        int g = l;
        const float* w0 = wtT;
        const float* w1 = wtT + 4096;
        const float* w2 = wtT + 8192;
        float acc[10];
#pragma unroll
        for (int c = 0; c < 10; c++) acc[c] = 0.f;
        for (int f = 0; f < 64; f++) {
            float wI = w0[f * 64 + g];
            float wA = w1[f * 64 + g];
            float wS = w2[f * 64 + g];
            const float* rf = &lds[w][f * 11];
            acc[0] += wI * rf[0];
            acc[1] += wA * rf[1];
            acc[2] += wA * rf[2];
            acc[3] += wA * rf[3];
#pragma unroll
            for (int c = 4; c < 10; c++) acc[c] += wS * rf[c];
        }
        float* co = comp + ((size_t)a * 64 + g) * 12;
        f32x4 c0 = {acc[0], acc[1], acc[2], acc[3]};
        f32x4 c1 = {acc[4], acc[5], acc[6], acc[7]};
        f32x4 c2 = {acc[8], acc[9], 0.f, 0.f};
        *(f32x4*)(co)     = c0;
        *(f32x4*)(co + 4) = c1;
        *(f32x4*)(co + 8) = c2;
        float* y = Yb + ((size_t)a * 64 + g) * 9;
        y[0] = acc[0] + acc[4];
        y[1] = acc[5] + acc[1];
        y[2] = acc[6] + acc[2];
        y[3] = acc[5] - acc[1];
        y[4] = acc[0] + acc[7];
        y[5] = acc[8] + acc[3];
        y[6] = acc[6] - acc[2];
        y[7] = acc[8] - acc[3];
        y[8] = acc[0] + acc[9];
    }
}

// ---------------- FUSED: edge-MLP (MFMA) + message gather + pair + lin2 ----------------
// 128 threads = 2 waves; each wave owns 2 consecutive atoms (contiguous CSR slots)
// and loops over <=16-edge chunks. Per chunk: gather rfv rows -> 3-layer hi/lo-split
// MFMA MLP (M=16 tile, identical per-row math to the old batched kernel -> bit-
// identical r) -> r-tile bf16 in wave-private LDS -> per-edge comp-gather
// accumulation in slot order (bit-identical sums). Then the lin2 epilogue per atom.
// Eliminates rbuf (123 MB write + 123 MB read) and overlaps MLP VALU work with
// gather memory latency across waves. No barriers (wave-private LDS).
// Per-wave LDS: h1[16][68] (4352 B) + h2[16][132] (8448 B) = 12800 B;
// rt[16][192] bf16 (6144 B) overlays h2 (dead after L3 frag extraction; every rt
// store depends on every h2 load via the MFMA chain, so ordering is by data dep);
// lin2 staging [64*11] f32 (2816 B) overlays h1 (dead). 25.6 KB/block -> 6 blk/CU.
__global__ __launch_bounds__(128) void fused_kernel(
    const int* __restrict__ off, const int* __restrict__ ebkt, const int* __restrict__ sbkt,
    const float* __restrict__ rfv, const float* __restrict__ dij,
    const float* __restrict__ b0, const float* __restrict__ b1, const float* __restrict__ b2,
    const unsigned short* __restrict__ f0h, const unsigned short* __restrict__ f0l,
    const unsigned short* __restrict__ f1h, const unsigned short* __restrict__ f1l,
    const unsigned short* __restrict__ f2h, const unsigned short* __restrict__ f2l,
    const float* __restrict__ comp, const float* __restrict__ Yb,
    const float* __restrict__ X, const float* __restrict__ charges,
    const float* __restrict__ wtT, float* __restrict__ out) {
    __shared__ float ldsbuf[2][3200];   // 12800 B per wave
    const int w = threadIdx.x >> 6;
    const int lane = threadIdx.x & 63;
    const int q = lane >> 4;
    const int c = lane & 15;
    const int a0 = blockIdx.x * 4 + w * 2;   // this wave's two atoms: a0, a0+1

    float* h1 = ldsbuf[w];                   // [16][68]
    float* h2 = ldsbuf[w] + 16 * 68;         // [16][132]
    unsigned short* rt = (unsigned short*)(ldsbuf[w] + 16 * 68); // [16][192] overlays h2
    float* l2s = ldsbuf[w];                  // [64*11] overlays h1 (lin2 phase)

    // hoist biases into registers (per-lane slice)
    float bb0[4], bb1[8], bb2[12];
#pragma unroll
    for (int nt = 0; nt < 4; nt++) bb0[nt] = b0[nt * 16 + c];
#pragma unroll
    for (int nt = 0; nt < 8; nt++) bb1[nt] = b1[nt * 16 + c];
#pragma unroll
    for (int nt = 0; nt < 12; nt++) bb2[nt] = b2[nt * 16 + c];

    const int beg = off[a0];
    const int mid = off[a0 + 1];
    const int end = off[a0 + 2];

    float m0[10], m1[10];
#pragma unroll
    for (int i = 0; i < 10; i++) { m0[i] = 0.f; m1[i] = 0.f; }

    for (int cb = beg; cb < end; cb += 16) {
        int cnt = end - cb;
        if (cnt > 16) cnt = 16;

        // ---- layer 1: A[16,32] x W0[32,64] -> h1 ----
        {
            int eL1 = ebkt[cb + (c < cnt ? c : 0)];
            float v[8];
            const float* p = rfv + (size_t)eL1 * 32 + q * 8;
            *(float4*)(v)     = *(const float4*)(p);
            *(float4*)(v + 4) = *(const float4*)(p + 4);
            bf16x8 a0h, a0l;
            split8(v, a0h, a0l);
#pragma unroll
            for (int nt = 0; nt < 4; nt++) {
                f32x4 acc = {bb0[nt], bb0[nt], bb0[nt], bb0[nt]};
                bf16x8 bh = *(const bf16x8*)(f0h + (size_t)(nt * 64 + lane) * 8);
                bf16x8 bl = *(const bf16x8*)(f0l + (size_t)(nt * 64 + lane) * 8);
                acc = MFMA16(a0l, bh, acc);
                acc = MFMA16(a0h, bl, acc);
                acc = MFMA16(a0h, bh, acc);
#pragma unroll
                for (int reg = 0; reg < 4; reg++)
                    h1[(q * 4 + reg) * 68 + nt * 16 + c] = silu(acc[reg]);
            }
        }

        // ---- layer 2: [16,64] x W1[64,128] -> h2 ----
        {
            bf16x8 ah[2], al[2];
#pragma unroll
            for (int ks = 0; ks < 2; ks++) {
                float v[8];
                const float* p = h1 + c * 68 + ks * 32 + q * 8;
                *(float4*)(v)     = *(const float4*)(p);
                *(float4*)(v + 4) = *(const float4*)(p + 4);
                split8(v, ah[ks], al[ks]);
            }
#pragma unroll
            for (int nt = 0; nt < 8; nt++) {
                f32x4 acc = {bb1[nt], bb1[nt], bb1[nt], bb1[nt]};
#pragma unroll
                for (int ks = 0; ks < 2; ks++) {
                    bf16x8 bh = *(const bf16x8*)(f1h + (size_t)((ks * 8 + nt) * 64 + lane) * 8);
                    bf16x8 bl = *(const bf16x8*)(f1l + (size_t)((ks * 8 + nt) * 64 + lane) * 8);
                    acc = MFMA16(al[ks], bh, acc);
                    acc = MFMA16(ah[ks], bl, acc);
                    acc = MFMA16(ah[ks], bh, acc);
                }
#pragma unroll
                for (int reg = 0; reg < 4; reg++)
                    h2[(q * 4 + reg) * 132 + nt * 16 + c] = silu(acc[reg]);
            }
        }

        // ---- layer 3: [16,128] x W2[128,192] -> rt (bf16, silu*cut) ----
        {
            bf16x8 ah[4], al[4];
#pragma unroll
            for (int ks = 0; ks < 4; ks++) {
                float v[8];
                const float* p = h2 + c * 132 + ks * 32 + q * 8;
                *(float4*)(v)     = *(const float4*)(p);
                *(float4*)(v + 4) = *(const float4*)(p + 4);
                split8(v, ah[ks], al[ks]);
            }
            float cut[4];
#pragma unroll
            for (int reg = 0; reg < 4; reg++) {
                int row = q * 4 + reg;
                int e2 = ebkt[cb + (row < cnt ? row : 0)];
                float d = dij[e2];
                cut[reg] = (d < 1.0f) ? 0.5f * (__cosf(PI_F * d) + 1.0f) : 0.0f;
            }
#pragma unroll
            for (int nt = 0; nt < 12; nt++) {
                f32x4 acc = {bb2[nt], bb2[nt], bb2[nt], bb2[nt]};
#pragma unroll
                for (int ks = 0; ks < 4; ks++) {
                    bf16x8 bh = *(const bf16x8*)(f2h + (size_t)((ks * 12 + nt) * 64 + lane) * 8);
                    bf16x8 bl = *(const bf16x8*)(f2l + (size_t)((ks * 12 + nt) * 64 + lane) * 8);
                    acc = MFMA16(al[ks], bh, acc);
                    acc = MFMA16(ah[ks], bl, acc);
                    acc = MFMA16(ah[ks], bh, acc);
                }
#pragma unroll
                for (int reg = 0; reg < 4; reg++)
                    rt[(q * 4 + reg) * 192 + nt * 16 + c] =
                        f2bf_rne(silu(acc[reg]) * cut[reg]);
            }
        }

        // ---- message accumulation over this chunk (slot order = old order) ----
        for (int i = 0; i < cnt; i++) {
            int slot = cb + i;
            int s = sbkt[slot];
            float r0 = bf2f(rt[i * 192 + lane * 3 + 0]);
            float r1 = bf2f(rt[i * 192 + lane * 3 + 1]);
            float r2 = bf2f(rt[i * 192 + lane * 3 + 2]);
            const float* cp = comp + ((size_t)s * 64 + lane) * 12;
            f32x4 c0 = *(const f32x4*)(cp);
            f32x4 c1 = *(const f32x4*)(cp + 4);
            f32x4 c2 = *(const f32x4*)(cp + 8);
            if (slot < mid) {
                m0[0] += r0 * c0.x;
                m0[1] += r1 * c0.y;
                m0[2] += r1 * c0.z;
                m0[3] += r1 * c0.w;
                m0[4] += r2 * c1.x;
                m0[5] += r2 * c1.y;
                m0[6] += r2 * c1.z;
                m0[7] += r2 * c1.w;
                m0[8] += r2 * c2.x;
                m0[9] += r2 * c2.y;
            } else {
                m1[0] += r0 * c0.x;
                m1[1] += r1 * c0.y;
                m1[2] += r1 * c0.z;
                m1[3] += r1 * c0.w;
                m1[4] += r2 * c1.x;
                m1[5] += r2 * c1.y;
                m1[6] += r2 * c1.z;
                m1[7] += r2 * c1.w;
                m1[8] += r2 * c2.x;
                m1[9] += r2 * c2.y;
            }
        }
    }

    // ---- per-atom pair + decompose + lin2 + epilogue (wave-private, no barriers) ----
#pragma unroll
    for (int at = 0; at < 2; at++) {
        int aa = a0 + at;
        float mm[10];
#pragma unroll
        for (int i = 0; i < 10; i++) mm[i] = (at == 0) ? m0[i] : m1[i];
        float qv = 1.0f + 0.1f * charges[aa];
        int l = lane;
        {
            float M[9];
            M[0] = mm[0] + mm[4]; M[1] = mm[5] + mm[1]; M[2] = mm[6] + mm[2];
            M[3] = mm[5] - mm[1]; M[4] = mm[0] + mm[7]; M[5] = mm[8] + mm[3];
            M[6] = mm[6] - mm[2]; M[7] = mm[8] - mm[3]; M[8] = mm[0] + mm[9];
            const float* yp = Yb + ((size_t)aa * 64 + l) * 9;
            float Y[9];
#pragma unroll
            for (int i = 0; i < 9; i++) Y[i] = yp[i];
            float P[9];
#pragma unroll
            for (int i = 0; i < 3; i++) {
#pragma unroll
                for (int j = 0; j < 3; j++) {
                    float s = 0.f;
#pragma unroll
                    for (int k = 0; k < 3; k++)
                        s += M[i * 3 + k] * Y[k * 3 + j] + Y[i * 3 + k] * M[k * 3 + j];
                    P[i * 3 + j] = qv * s;
                }
            }
            float t2 = 0.f;
#pragma unroll
            for (int i = 0; i < 9; i++) t2 += P[i] * P[i];
            float inv = 1.0f / (t2 + 1.0f);
            float iso = (P[0] + P[4] + P[8]) * (1.0f / 3.0f);
            float* o = &l2s[l * 11];
            o[0] = iso * inv;
            o[1] = 0.5f * (P[1] - P[3]) * inv;
            o[2] = 0.5f * (P[2] - P[6]) * inv;
            o[3] = 0.5f * (P[5] - P[7]) * inv;
            o[4] = (P[0] - iso) * inv;
            o[5] = 0.5f * (P[1] + P[3]) * inv;
            o[6] = 0.5f * (P[2] + P[6]) * inv;
            o[7] = (P[4] - iso) * inv;
            o[8] = 0.5f * (P[5] + P[7]) * inv;
            o[9] = (P[8] - iso) * inv;
        }
        {
            int g = l;
            const float* w3 = wtT + 3 * 4096;
            const float* w4 = wtT + 4 * 4096;
            const float* w5 = wtT + 5 * 4096;
            float acc[10];
#pragma unroll
            for (int cc = 0; cc < 10; cc++) acc[cc] = 0.f;
            for (int f = 0; f < 64; f++) {
                float wI = w3[f * 64 + g];
                float wA = w4[f * 64 + g];
                float wS = w5[f * 64 + g];
                const float* rf = &l2s[f * 11];
                acc[0] += wI * rf[0];
                acc[1] += wA * rf[1];
                acc[2] += wA * rf[2];
                acc[3] += wA * rf[3];
#pragma unroll
                for (int cc = 4; cc < 10; cc++) acc[cc] += wS * rf[cc];
            }
            float D[9];
            D[0] = acc[0] + acc[4]; D[1] = acc[5] + acc[1]; D[2] = acc[6] + acc[2];
            D[3] = acc[5] - acc[1]; D[4] = acc[0] + acc[7]; D[5] = acc[8] + acc[3];
            D[6] = acc[6] - acc[2]; D[7] = acc[8] - acc[3]; D[8] = acc[0] + acc[9];

            const float* x = X + ((size_t)aa * 64 + g) * 9;
            float xv[9];
#pragma unroll
            for (int i = 0; i < 9; i++) xv[i] = x[i];
            float t2 = 0.f;
#pragma unroll
            for (int i = 0; i < 9; i++) t2 += xv[i] * xv[i];
            float invn = 1.0f / (t2 + 1.0f);
#pragma unroll
            for (int i = 0; i < 9; i++) xv[i] *= invn;

            float DD[9];
#pragma unroll
            for (int i = 0; i < 3; i++) {
#pragma unroll
                for (int j = 0; j < 3; j++) {
                    float s = 0.f;
#pragma unroll
                    for (int k = 0; k < 3; k++) s += D[i * 3 + k] * D[k * 3 + j];
                    DD[i * 3 + j] = s;
                }
            }
            float* op = out + ((size_t)aa * 64 + g) * 9;
#pragma unroll
            for (int i = 0; i < 9; i++) op[i] = xv[i] + D[i] + qv * DD[i];
        }
    }
}

extern "C" void kernel_launch(void* const* d_in, const int* in_sizes, int n_in,
                              void* d_out, int out_size, void* d_ws, size_t ws_size,
                              hipStream_t stream) {
    const float* X       = (const float*)d_in[0];
    const int*   pair    = (const int*)d_in[1];
    const float* dij     = (const float*)d_in[2];
    const float* rfv     = (const float*)d_in[3];
    const float* charges = (const float*)d_in[4];
    const float* W0      = (const float*)d_in[5];
    const float* b0      = (const float*)d_in[6];
    const float* W1      = (const float*)d_in[7];
    const float* b1      = (const float*)d_in[8];
    const float* W2      = (const float*)d_in[9];
    const float* b2      = (const float*)d_in[10];
    const float* Wt      = (const float*)d_in[11];
    float* out = (float*)d_out;

    const int* dst = pair;        // pair_indices[0] (scatter)
    const int* src = pair + NE;   // pair_indices[1] (gather)

    // ---- workspace layout (~65 MB) ----
    char* ws = (char*)d_ws;
    size_t ofs = 0;
    auto alloc = [&](size_t bytes) {
        void* p = ws + ofs;
        ofs += (bytes + 255) & ~(size_t)255;
        return p;
    };
    float* wtT  = (float*)alloc((size_t)6 * 4096 * 4);                 // 96 KB
    unsigned short* f0h = (unsigned short*)alloc(2048 * 2);
    unsigned short* f0l = (unsigned short*)alloc(2048 * 2);
    unsigned short* f1h = (unsigned short*)alloc(8192 * 2);
    unsigned short* f1l = (unsigned short*)alloc(8192 * 2);
    unsigned short* f2h = (unsigned short*)alloc(24576 * 2);
    unsigned short* f2l = (unsigned short*)alloc(24576 * 2);
    float* comp = (float*)alloc((size_t)N_ATOMS * FDIM * 12 * 4);      // 61.4 MB (padded)
    int* deg    = (int*)alloc((size_t)N_ATOMS * 4);
    int* offarr = (int*)alloc((size_t)(N_ATOMS + 1) * 4);
    int* cursor = (int*)alloc((size_t)N_ATOMS * 4);
    int* ebkt   = (int*)alloc((size_t)NE * 4);
    int* sbkt   = (int*)alloc((size_t)NE * 4);
    float* Yb   = out;  // reuse d_out as Y scratch; each wave reads its own rows
                        // before overwriting them in the fused epilogue

    hipMemsetAsync(deg, 0, (size_t)N_ATOMS * 4, stream);
    hipMemsetAsync(cursor, 0, (size_t)N_ATOMS * 4, stream);

    transpose_kernel<<<(24576 + 255) / 256, 256, 0, stream>>>(Wt, wtT);
    wfrag_kernel<<<(34816 + 255) / 256, 256, 0, stream>>>(
        W0, W1, W2, f0h, f0l, f1h, f1l, f2h, f2l);
    hist_kernel<<<NE / 256, 256, 0, stream>>>(dst, deg);
    scan_kernel<<<1, 1024, 0, stream>>>(deg, offarr);
    fill_kernel<<<NE / 256, 256, 0, stream>>>(dst, src, offarr, cursor, ebkt, sbkt);

    lin1_kernel<<<N_ATOMS / 4, 256, 0, stream>>>(X, wtT, comp, Yb);

    fused_kernel<<<N_ATOMS / 4, 128, 0, stream>>>(
        offarr, ebkt, sbkt, rfv, dij, b0, b1, b2,
        f0h, f0l, f1h, f1l, f2h, f2l, comp, Yb, X, charges, wtT, out);
}

// Round 6
// 612.222 us; speedup vs baseline: 2.3241x; 2.3241x over previous
//
#include <hip/hip_runtime.h>
#include <hip/hip_bf16.h>
#include <cmath>

#define N_ATOMS 20000
#define NE      320000
#define FDIM    64
#define NRBF    32
#define PI_F    3.14159265358979323846f

typedef __attribute__((ext_vector_type(8))) short bf16x8;
typedef __attribute__((ext_vector_type(4))) float f32x4;

#define MFMA16(a, b, c) __builtin_amdgcn_mfma_f32_16x16x32_bf16(a, b, c, 0, 0, 0)

__device__ __forceinline__ float silu(float x) {
    return x / (1.0f + __expf(-x));
}

__device__ __forceinline__ unsigned short f2bf_rne(float x) {
    unsigned u = __float_as_uint(x);
    u += 0x7fffu + ((u >> 16) & 1u);
    return (unsigned short)(u >> 16);
}

// split fp32 -> hi (truncated bf16) + lo (RNE bf16 of residual); hi+lo ~ 2^-17 rel
__device__ __forceinline__ void split8(const float* v, bf16x8& hi, bf16x8& lo) {
#pragma unroll
    for (int j = 0; j < 8; j++) {
        unsigned u = __float_as_uint(v[j]);
        float hf = __uint_as_float(u & 0xffff0000u);
        hi[j] = (short)(u >> 16);
        lo[j] = (short)f2bf_rne(v[j] - hf);
    }
}

// ---------------- merged prep: transpose + wfrag + hist (independent ranges) ----------------
__global__ void prep_kernel(const float* __restrict__ Wt, float* __restrict__ wtT,
                            const float* __restrict__ W0, const float* __restrict__ W1,
                            const float* __restrict__ W2,
                            unsigned short* __restrict__ f0h, unsigned short* __restrict__ f0l,
                            unsigned short* __restrict__ f1h, unsigned short* __restrict__ f1l,
                            unsigned short* __restrict__ f2h, unsigned short* __restrict__ f2l,
                            const int* __restrict__ dst, int* __restrict__ deg) {
    int idx = blockIdx.x * 256 + threadIdx.x;
    if (idx < 24576) {
        // transpose wtT[k][f][g] from Wt[k][g][f]
        int k = idx >> 12;
        int r = idx & 4095;
        int g = r >> 6;
        int f = r & 63;
        wtT[k * 4096 + f * 64 + g] = Wt[idx];
    } else if (idx < 59392) {
        // weight fragment prep: hi/lo bf16 planes, MFMA B-layout
        int t = idx - 24576;
        const float* W;
        unsigned short *fh, *fl;
        int K, NT;
        if (t < 2048)       { W = W0; fh = f0h; fl = f0l;               K = 32;  NT = 4; }
        else if (t < 10240) { W = W1; fh = f1h; fl = f1l; t -= 2048;    K = 64;  NT = 8; }
        else                { W = W2; fh = f2h; fl = f2l; t -= 10240;   K = 128; NT = 12; }
        int j = t & 7;
        int lane = (t >> 3) & 63;
        int rest = t >> 9;
        int nt = rest % NT;
        int ks = rest / NT;
        int k = ks * 32 + ((lane >> 4) & 3) * 8 + j;
        int n = nt * 16 + (lane & 15);
        float w = W[n * K + k];
        unsigned u = __float_as_uint(w);
        float hf = __uint_as_float(u & 0xffff0000u);
        fh[t] = (unsigned short)(u >> 16);
        fl[t] = f2bf_rne(w - hf);
    } else if (idx < 59392 + NE) {
        int e = idx - 59392;
        atomicAdd(&deg[dst[e]], 1);
    }
}

__global__ void scan_kernel(const int* __restrict__ deg, int* __restrict__ off) {
    __shared__ int part[1024];
    int t = threadIdx.x;
    const int CH = (N_ATOMS + 1023) / 1024; // 20
    int base = t * CH;
    int s = 0;
    for (int i = 0; i < CH; i++) {
        int idx = base + i;
        if (idx < N_ATOMS) s += deg[idx];
    }
    part[t] = s;
    __syncthreads();
    for (int ofs = 1; ofs < 1024; ofs <<= 1) {
        int v = (t >= ofs) ? part[t - ofs] : 0;
        __syncthreads();
        part[t] += v;
        __syncthreads();
    }
    int run = (t == 0) ? 0 : part[t - 1];
    for (int i = 0; i < CH; i++) {
        int idx = base + i;
        if (idx < N_ATOMS) {
            off[idx] = run;
            run += deg[idx];
        }
    }
    if (t == 1023) off[N_ATOMS] = run;
}

// slotOf[e] = CSR slot of edge e; sbkt[slot] = src atom. The mlp part writes
// r directly at the slot so the msg gather reads r SEQUENTIALLY.
__global__ void fill_kernel(const int* __restrict__ dst, const int* __restrict__ srcArr,
                            const int* __restrict__ off, int* __restrict__ cursor,
                            int* __restrict__ sbkt, int* __restrict__ slotOf) {
    int e = blockIdx.x * 256 + threadIdx.x;
    if (e >= NE) return;
    int d = dst[e];
    int pos = atomicAdd(&cursor[d], 1);
    int slot = off[d] + pos;
    sbkt[slot] = srcArr[e];
    slotOf[e] = slot;
}

// ---------------- merged mlp (MFMA edge MLP) + lin1 (decompose+linear) ----------------
// Heterogeneous blocks, 128 threads each: even blockIdx -> mlp block (64 edges,
// 2 waves x 32 edges, R3-proven body verbatim); odd blockIdx -> lin1 block
// (4 atoms, 2 waves x 2 atoms, R3 body verbatim, wave-private LDS slice).
// Rationale (R5 post-mortem: full fusion failed at 1423us): the two phases need
// different parallel shapes; co-scheduling whole blocks keeps each shape optimal
// while lin1's memory waves fill mlp's latency stalls (mlp: 52% VALU, 12% HBM).
// LDS union = mlp's 51.2 KB -> 3 blocks/CU as before.
#define H1S 68   // 64 + 4 pad dwords
#define H2S 132  // 128 + 4 pad
__global__ __launch_bounds__(128) void mlp_lin1_kernel(
    const float* __restrict__ rfv, const float* __restrict__ dij,
    const float* __restrict__ b0, const float* __restrict__ b1, const float* __restrict__ b2,
    const unsigned short* __restrict__ f0h, const unsigned short* __restrict__ f0l,
    const unsigned short* __restrict__ f1h, const unsigned short* __restrict__ f1l,
    const unsigned short* __restrict__ f2h, const unsigned short* __restrict__ f2l,
    const int* __restrict__ slotOf, __hip_bfloat16* __restrict__ r,
    const float* __restrict__ X, const float* __restrict__ wtT,
    float* __restrict__ comp, float* __restrict__ Yb) {
    __shared__ float h1s[2][32][H1S];
    __shared__ float h2s[2][32][H2S];
    const int w = threadIdx.x >> 6;
    const int lane = threadIdx.x & 63;

    if (blockIdx.x & 1) {
        // ================= lin1 part: 4 atoms, wave-private =================
        int id = blockIdx.x >> 1;
        float* stage = ((float*)h1s) + w * 704;   // 64*11 floats, wave-private
#pragma unroll
        for (int at = 0; at < 2; at++) {
            int a = id * 4 + w * 2 + at;
            int l = lane;
            {
                const float* x = X + ((size_t)a * 64 + l) * 9;
                float v[9];
#pragma unroll
                for (int i = 0; i < 9; i++) v[i] = x[i];
                float t2 = 0.f;
#pragma unroll
                for (int i = 0; i < 9; i++) t2 += v[i] * v[i];
                float inv = 1.0f / (t2 + 1.0f);
#pragma unroll
                for (int i = 0; i < 9; i++) v[i] *= inv;
                float iso = (v[0] + v[4] + v[8]) * (1.0f / 3.0f);
                float* o = &stage[l * 11];
                o[0] = iso;
                o[1] = 0.5f * (v[1] - v[3]);
                o[2] = 0.5f * (v[2] - v[6]);
                o[3] = 0.5f * (v[5] - v[7]);
                o[4] = v[0] - iso;
                o[5] = 0.5f * (v[1] + v[3]);
                o[6] = 0.5f * (v[2] + v[6]);
                o[7] = v[4] - iso;
                o[8] = 0.5f * (v[5] + v[7]);
                o[9] = v[8] - iso;
            }
            {
                int g = l;
                const float* w0 = wtT;
                const float* w1 = wtT + 4096;
                const float* w2 = wtT + 8192;
                float acc[10];
#pragma unroll
                for (int c = 0; c < 10; c++) acc[c] = 0.f;
                for (int f = 0; f < 64; f++) {
                    float wI = w0[f * 64 + g];
                    float wA = w1[f * 64 + g];
                    float wS = w2[f * 64 + g];
                    const float* rf = &stage[f * 11];
                    acc[0] += wI * rf[0];
                    acc[1] += wA * rf[1];
                    acc[2] += wA * rf[2];
                    acc[3] += wA * rf[3];
#pragma unroll
                    for (int c = 4; c < 10; c++) acc[c] += wS * rf[c];
                }
                float* co = comp + ((size_t)a * 64 + g) * 12;
                float4 c0 = {acc[0], acc[1], acc[2], acc[3]};
                float4 c1 = {acc[4], acc[5], acc[6], acc[7]};
                float4 c2 = {acc[8], acc[9], 0.f, 0.f};
                *(float4*)(co)     = c0;
                *(float4*)(co + 4) = c1;
                *(float4*)(co + 8) = c2;
                float* y = Yb + ((size_t)a * 64 + g) * 9;
                y[0] = acc[0] + acc[4];
                y[1] = acc[5] + acc[1];
                y[2] = acc[6] + acc[2];
                y[3] = acc[5] - acc[1];
                y[4] = acc[0] + acc[7];
                y[5] = acc[8] + acc[3];
                y[6] = acc[6] - acc[2];
                y[7] = acc[8] - acc[3];
                y[8] = acc[0] + acc[9];
            }
        }
        return;
    }

    // ================= mlp part: 64 edges (R3 body verbatim) =================
    const int q = lane >> 4;
    const int c = lane & 15;
    const int e0 = ((blockIdx.x >> 1) * 2 + w) * 32;
    float (*h1)[H1S] = h1s[w];
    float (*h2)[H2S] = h2s[w];

    // ---- layer 1: [32,32] x [32,64] -> h1 ----
    {
        bf16x8 ah[2], al[2];
#pragma unroll
        for (int mt = 0; mt < 2; mt++) {
            float v[8];
            const float* p = rfv + (size_t)(e0 + mt * 16 + c) * 32 + q * 8;
            *(float4*)(v)     = *(const float4*)(p);
            *(float4*)(v + 4) = *(const float4*)(p + 4);
            split8(v, ah[mt], al[mt]);
        }
#pragma unroll
        for (int nt = 0; nt < 4; nt++) {
            float bias = b0[nt * 16 + c];
            f32x4 acc[2];
            acc[0] = {bias, bias, bias, bias};
            acc[1] = acc[0];
            bf16x8 bh = *(const bf16x8*)(f0h + (size_t)(nt * 64 + lane) * 8);
            bf16x8 bl = *(const bf16x8*)(f0l + (size_t)(nt * 64 + lane) * 8);
#pragma unroll
            for (int mt = 0; mt < 2; mt++) {
                acc[mt] = MFMA16(al[mt], bh, acc[mt]);
                acc[mt] = MFMA16(ah[mt], bl, acc[mt]);
                acc[mt] = MFMA16(ah[mt], bh, acc[mt]);
            }
#pragma unroll
            for (int mt = 0; mt < 2; mt++)
#pragma unroll
                for (int reg = 0; reg < 4; reg++)
                    h1[mt * 16 + q * 4 + reg][nt * 16 + c] = silu(acc[mt][reg]);
        }
    }

    // ---- layer 2: [32,64] x [64,128] -> h2 ----
    {
        bf16x8 ah[2][2], al[2][2];
#pragma unroll
        for (int mt = 0; mt < 2; mt++)
#pragma unroll
            for (int ks = 0; ks < 2; ks++) {
                float v[8];
                const float* p = &h1[mt * 16 + c][ks * 32 + q * 8];
                *(float4*)(v)     = *(const float4*)(p);
                *(float4*)(v + 4) = *(const float4*)(p + 4);
                split8(v, ah[mt][ks], al[mt][ks]);
            }
#pragma unroll
        for (int nt = 0; nt < 8; nt++) {
            float bias = b1[nt * 16 + c];
            f32x4 acc[2];
            acc[0] = {bias, bias, bias, bias};
            acc[1] = acc[0];
#pragma unroll
            for (int ks = 0; ks < 2; ks++) {
                bf16x8 bh = *(const bf16x8*)(f1h + (size_t)((ks * 8 + nt) * 64 + lane) * 8);
                bf16x8 bl = *(const bf16x8*)(f1l + (size_t)((ks * 8 + nt) * 64 + lane) * 8);
#pragma unroll
                for (int mt = 0; mt < 2; mt++) {
                    acc[mt] = MFMA16(al[mt][ks], bh, acc[mt]);
                    acc[mt] = MFMA16(ah[mt][ks], bl, acc[mt]);
                    acc[mt] = MFMA16(ah[mt][ks], bh, acc[mt]);
                }
            }
#pragma unroll
            for (int mt = 0; mt < 2; mt++)
#pragma unroll
                for (int reg = 0; reg < 4; reg++)
                    h2[mt * 16 + q * 4 + reg][nt * 16 + c] = silu(acc[mt][reg]);
        }
    }

    // ---- layer 3: [32,128] x [128,192] -> r at CSR slot (silu * cutoff, bf16) ----
    {
        bf16x8 ah[2][4], al[2][4];
#pragma unroll
        for (int mt = 0; mt < 2; mt++)
#pragma unroll
            for (int ks = 0; ks < 4; ks++) {
                float v[8];
                const float* p = &h2[mt * 16 + c][ks * 32 + q * 8];
                *(float4*)(v)     = *(const float4*)(p);
                *(float4*)(v + 4) = *(const float4*)(p + 4);
                split8(v, ah[mt][ks], al[mt][ks]);
            }
        float cut[2][4];
        int srow[2][4];
#pragma unroll
        for (int mt = 0; mt < 2; mt++)
#pragma unroll
            for (int reg = 0; reg < 4; reg++) {
                int e = e0 + mt * 16 + q * 4 + reg;
                float d = dij[e];
                cut[mt][reg] = (d < 1.0f) ? 0.5f * (__cosf(PI_F * d) + 1.0f) : 0.0f;
                srow[mt][reg] = slotOf[e];
            }
#pragma unroll
        for (int nt = 0; nt < 12; nt++) {
            float bias = b2[nt * 16 + c];
            f32x4 acc[2];
            acc[0] = {bias, bias, bias, bias};
            acc[1] = acc[0];
#pragma unroll
            for (int ks = 0; ks < 4; ks++) {
                bf16x8 bh = *(const bf16x8*)(f2h + (size_t)((ks * 12 + nt) * 64 + lane) * 8);
                bf16x8 bl = *(const bf16x8*)(f2l + (size_t)((ks * 12 + nt) * 64 + lane) * 8);
#pragma unroll
                for (int mt = 0; mt < 2; mt++) {
                    acc[mt] = MFMA16(al[mt][ks], bh, acc[mt]);
                    acc[mt] = MFMA16(ah[mt][ks], bl, acc[mt]);
                    acc[mt] = MFMA16(ah[mt][ks], bh, acc[mt]);
                }
            }
#pragma unroll
            for (int mt = 0; mt < 2; mt++)
#pragma unroll
                for (int reg = 0; reg < 4; reg++)
                    r[(size_t)srow[mt][reg] * 192 + nt * 16 + c] =
                        __float2bfloat16(silu(acc[mt][reg]) * cut[mt][reg]);
        }
    }
}

// ---------------- fused message passing + pair + lin2 + epilogue (R3 verbatim) ----------------
__global__ __launch_bounds__(256) void msg_lin2_kernel(
    const int* __restrict__ off, const int* __restrict__ sbkt,
    const __hip_bfloat16* __restrict__ r,
    const float* __restrict__ comp, const float* __restrict__ Yb,
    const float* __restrict__ X, const float* __restrict__ charges,
    const float* __restrict__ wtT, float* __restrict__ out) {
    __shared__ float lds[4][64 * 11];
    int w = threadIdx.x >> 6;
    int l = threadIdx.x & 63;
    int a = blockIdx.x * 4 + w;
    float q = 1.0f + 0.1f * charges[a];

    // ---- message accumulation ----
    float m[10];
#pragma unroll
    for (int c = 0; c < 10; c++) m[c] = 0.f;
    {
        int beg = off[a], end = off[a + 1];
        if (beg < end) {
            __hip_bfloat16 ra, rb, rc;
            float4 c0, c1, c2;
            {
                const __hip_bfloat16* rp = r + (size_t)beg * 192 + l * 3;
                ra = rp[0]; rb = rp[1]; rc = rp[2];
                const float* cp = comp + ((size_t)sbkt[beg] * 64 + l) * 12;
                c0 = *(const float4*)(cp);
                c1 = *(const float4*)(cp + 4);
                c2 = *(const float4*)(cp + 8);
            }
            for (int i = beg + 1; i < end; i++) {
                const __hip_bfloat16* rp = r + (size_t)i * 192 + l * 3;
                __hip_bfloat16 na = rp[0], nb = rp[1], nc = rp[2];
                const float* cp = comp + ((size_t)sbkt[i] * 64 + l) * 12;
                float4 n0 = *(const float4*)(cp);
                float4 n1 = *(const float4*)(cp + 4);
                float4 n2 = *(const float4*)(cp + 8);
                float r0 = __bfloat162float(ra);
                float r1 = __bfloat162float(rb);
                float r2 = __bfloat162float(rc);
                m[0] += r0 * c0.x;
                m[1] += r1 * c0.y;
                m[2] += r1 * c0.z;
                m[3] += r1 * c0.w;
                m[4] += r2 * c1.x;
                m[5] += r2 * c1.y;
                m[6] += r2 * c1.z;
                m[7] += r2 * c1.w;
                m[8] += r2 * c2.x;
                m[9] += r2 * c2.y;
                ra = na; rb = nb; rc = nc;
                c0 = n0; c1 = n1; c2 = n2;
            }
            float r0 = __bfloat162float(ra);
            float r1 = __bfloat162float(rb);
            float r2 = __bfloat162float(rc);
            m[0] += r0 * c0.x;
            m[1] += r1 * c0.y;
            m[2] += r1 * c0.z;
            m[3] += r1 * c0.w;
            m[4] += r2 * c1.x;
            m[5] += r2 * c1.y;
            m[6] += r2 * c1.z;
            m[7] += r2 * c1.w;
            m[8] += r2 * c2.x;
            m[9] += r2 * c2.y;
        }
    }

    // ---- pair term + decompose ----
    {
        float M[9];
        M[0] = m[0] + m[4]; M[1] = m[5] + m[1]; M[2] = m[6] + m[2];
        M[3] = m[5] - m[1]; M[4] = m[0] + m[7]; M[5] = m[8] + m[3];
        M[6] = m[6] - m[2]; M[7] = m[8] - m[3]; M[8] = m[0] + m[9];
        const float* yp = Yb + ((size_t)a * 64 + l) * 9;
        float Y[9];
#pragma unroll
        for (int i = 0; i < 9; i++) Y[i] = yp[i];
        float P[9];
#pragma unroll
        for (int i = 0; i < 3; i++) {
#pragma unroll
            for (int j = 0; j < 3; j++) {
                float s = 0.f;
#pragma unroll
                for (int k = 0; k < 3; k++)
                    s += M[i * 3 + k] * Y[k * 3 + j] + Y[i * 3 + k] * M[k * 3 + j];
                P[i * 3 + j] = q * s;
            }
        }
        float t2 = 0.f;
#pragma unroll
        for (int i = 0; i < 9; i++) t2 += P[i] * P[i];
        float inv = 1.0f / (t2 + 1.0f);
        float iso = (P[0] + P[4] + P[8]) * (1.0f / 3.0f);
        float* o = &lds[w][l * 11];
        o[0] = iso * inv;
        o[1] = 0.5f * (P[1] - P[3]) * inv;
        o[2] = 0.5f * (P[2] - P[6]) * inv;
        o[3] = 0.5f * (P[5] - P[7]) * inv;
        o[4] = (P[0] - iso) * inv;
        o[5] = 0.5f * (P[1] + P[3]) * inv;
        o[6] = 0.5f * (P[2] + P[6]) * inv;
        o[7] = (P[4] - iso) * inv;
        o[8] = 0.5f * (P[5] + P[7]) * inv;
        o[9] = (P[8] - iso) * inv;
    }
    __syncthreads();
    {
        int g = l;
        const float* w3 = wtT + 3 * 4096;
        const float* w4 = wtT + 4 * 4096;
        const float* w5 = wtT + 5 * 4096;
        float acc[10];
#pragma unroll
        for (int c = 0; c < 10; c++) acc[c] = 0.f;
        for (int f = 0; f < 64; f++) {
            float wI = w3[f * 64 + g];
            float wA = w4[f * 64 + g];
            float wS = w5[f * 64 + g];
            const float* rf = &lds[w][f * 11];
            acc[0] += wI * rf[0];
            acc[1] += wA * rf[1];
            acc[2] += wA * rf[2];
            acc[3] += wA * rf[3];
#pragma unroll
            for (int c = 4; c < 10; c++) acc[c] += wS * rf[c];
        }
        float D[9];
        D[0] = acc[0] + acc[4]; D[1] = acc[5] + acc[1]; D[2] = acc[6] + acc[2];
        D[3] = acc[5] - acc[1]; D[4] = acc[0] + acc[7]; D[5] = acc[8] + acc[3];
        D[6] = acc[6] - acc[2]; D[7] = acc[8] - acc[3]; D[8] = acc[0] + acc[9];

        const float* x = X + ((size_t)a * 64 + g) * 9;
        float xv[9];
#pragma unroll
        for (int i = 0; i < 9; i++) xv[i] = x[i];
        float t2 = 0.f;
#pragma unroll
        for (int i = 0; i < 9; i++) t2 += xv[i] * xv[i];
        float invn = 1.0f / (t2 + 1.0f);
#pragma unroll
        for (int i = 0; i < 9; i++) xv[i] *= invn;

        float DD[9];
#pragma unroll
        for (int i = 0; i < 3; i++) {
#pragma unroll
            for (int j = 0; j < 3; j++) {
                float s = 0.f;
#pragma unroll
                for (int k = 0; k < 3; k++) s += D[i * 3 + k] * D[k * 3 + j];
                DD[i * 3 + j] = s;
            }
        }
        float* op = out + ((size_t)a * 64 + g) * 9;
#pragma unroll
        for (int i = 0; i < 9; i++) op[i] = xv[i] + D[i] + q * DD[i];
    }
}

extern "C" void kernel_launch(void* const* d_in, const int* in_sizes, int n_in,
                              void* d_out, int out_size, void* d_ws, size_t ws_size,
                              hipStream_t stream) {
    const float* X       = (const float*)d_in[0];
    const int*   pair    = (const int*)d_in[1];
    const float* dij     = (const float*)d_in[2];
    const float* rfv     = (const float*)d_in[3];
    const float* charges = (const float*)d_in[4];
    const float* W0      = (const float*)d_in[5];
    const float* b0      = (const float*)d_in[6];
    const float* W1      = (const float*)d_in[7];
    const float* b1      = (const float*)d_in[8];
    const float* W2      = (const float*)d_in[9];
    const float* b2      = (const float*)d_in[10];
    const float* Wt      = (const float*)d_in[11];
    float* out = (float*)d_out;

    const int* dst = pair;        // pair_indices[0] (scatter)
    const int* src = pair + NE;   // pair_indices[1] (gather)

    // ---- workspace layout (~190 MB) ----
    char* ws = (char*)d_ws;
    size_t ofs = 0;
    auto alloc = [&](size_t bytes) {
        void* p = ws + ofs;
        ofs += (bytes + 255) & ~(size_t)255;
        return p;
    };
    float* wtT  = (float*)alloc((size_t)6 * 4096 * 4);                 // 96 KB
    unsigned short* f0h = (unsigned short*)alloc(2048 * 2);
    unsigned short* f0l = (unsigned short*)alloc(2048 * 2);
    unsigned short* f1h = (unsigned short*)alloc(8192 * 2);
    unsigned short* f1l = (unsigned short*)alloc(8192 * 2);
    unsigned short* f2h = (unsigned short*)alloc(24576 * 2);
    unsigned short* f2l = (unsigned short*)alloc(24576 * 2);
    float* comp = (float*)alloc((size_t)N_ATOMS * FDIM * 12 * 4);      // 61.4 MB (padded)
    __hip_bfloat16* rbuf = (__hip_bfloat16*)alloc((size_t)NE * 192 * 2); // 122.9 MB
    int* deg    = (int*)alloc((size_t)N_ATOMS * 4);
    int* offarr = (int*)alloc((size_t)(N_ATOMS + 1) * 4);
    int* cursor = (int*)alloc((size_t)N_ATOMS * 4);
    int* sbkt   = (int*)alloc((size_t)NE * 4);
    int* slotOf = (int*)alloc((size_t)NE * 4);
    float* Yb   = out;  // reuse d_out as Y scratch; fully overwritten by msg_lin2

    hipMemsetAsync(deg, 0, (size_t)N_ATOMS * 4, stream);
    hipMemsetAsync(cursor, 0, (size_t)N_ATOMS * 4, stream);

    prep_kernel<<<(59392 + NE + 255) / 256, 256, 0, stream>>>(
        Wt, wtT, W0, W1, W2, f0h, f0l, f1h, f1l, f2h, f2l, dst, deg);
    scan_kernel<<<1, 1024, 0, stream>>>(deg, offarr);
    fill_kernel<<<NE / 256, 256, 0, stream>>>(dst, src, offarr, cursor, sbkt, slotOf);

    // even blocks: 5000 mlp blocks (64 edges each); odd blocks: 5000 lin1 blocks (4 atoms)
    mlp_lin1_kernel<<<10000, 128, 0, stream>>>(
        rfv, dij, b0, b1, b2, f0h, f0l, f1h, f1l, f2h, f2l, slotOf, rbuf,
        X, wtT, comp, Yb);

    msg_lin2_kernel<<<N_ATOMS / 4, 256, 0, stream>>>(
        offarr, sbkt, rbuf, comp, Yb, X, charges, wtT, out);
}

// Round 9
// 545.342 us; speedup vs baseline: 2.6092x; 1.1226x over previous
//
#include <hip/hip_runtime.h>
#include <hip/hip_bf16.h>
#include <cmath>

#define N_ATOMS 20000
#define NE      320000
#define FDIM    64
#define NRBF    32
#define PI_F    3.14159265358979323846f

typedef __attribute__((ext_vector_type(8))) short bf16x8;
typedef __attribute__((ext_vector_type(4))) float f32x4;

#define MFMA16(a, b, c) __builtin_amdgcn_mfma_f32_16x16x32_bf16(a, b, c, 0, 0, 0)

__device__ __forceinline__ float silu(float x) {
    return x / (1.0f + __expf(-x));
}

__device__ __forceinline__ unsigned short f2bf_rne(float x) {
    unsigned u = __float_as_uint(x);
    u += 0x7fffu + ((u >> 16) & 1u);
    return (unsigned short)(u >> 16);
}

// split fp32 -> hi (truncated bf16) + lo (RNE bf16 of residual); hi+lo ~ 2^-17 rel
__device__ __forceinline__ void split8(const float* v, bf16x8& hi, bf16x8& lo) {
#pragma unroll
    for (int j = 0; j < 8; j++) {
        unsigned u = __float_as_uint(v[j]);
        float hf = __uint_as_float(u & 0xffff0000u);
        hi[j] = (short)(u >> 16);
        lo[j] = (short)f2bf_rne(v[j] - hf);
    }
}

// ---------------- merged prep: transpose + wfrag + hist (independent ranges) ----------------
// R6 evidence: this regular-dispatch merge saved ~35us of launch/ramp overhead.
// (The R7 cooperative-launch variant broke the harness -- do NOT use coop here.)
__global__ void prep_kernel(const float* __restrict__ Wt, float* __restrict__ wtT,
                            const float* __restrict__ W0, const float* __restrict__ W1,
                            const float* __restrict__ W2,
                            unsigned short* __restrict__ f0h, unsigned short* __restrict__ f0l,
                            unsigned short* __restrict__ f1h, unsigned short* __restrict__ f1l,
                            unsigned short* __restrict__ f2h, unsigned short* __restrict__ f2l,
                            const int* __restrict__ dst, int* __restrict__ deg) {
    int idx = blockIdx.x * 256 + threadIdx.x;
    if (idx < 24576) {
        // transpose wtT[k][f][g] from Wt[k][g][f]
        int k = idx >> 12;
        int r = idx & 4095;
        int g = r >> 6;
        int f = r & 63;
        wtT[k * 4096 + f * 64 + g] = Wt[idx];
    } else if (idx < 59392) {
        // weight fragment prep: hi/lo bf16 planes, MFMA B-layout
        int t = idx - 24576;
        const float* W;
        unsigned short *fh, *fl;
        int K, NT;
        if (t < 2048)       { W = W0; fh = f0h; fl = f0l;             K = 32;  NT = 4; }
        else if (t < 10240) { W = W1; fh = f1h; fl = f1l; t -= 2048;  K = 64;  NT = 8; }
        else                { W = W2; fh = f2h; fl = f2l; t -= 10240; K = 128; NT = 12; }
        int j = t & 7;
        int lane = (t >> 3) & 63;
        int rest = t >> 9;
        int nt = rest % NT;
        int ks = rest / NT;
        int k = ks * 32 + ((lane >> 4) & 3) * 8 + j;
        int n = nt * 16 + (lane & 15);
        float w = W[n * K + k];
        unsigned u = __float_as_uint(w);
        float hf = __uint_as_float(u & 0xffff0000u);
        fh[t] = (unsigned short)(u >> 16);
        fl[t] = f2bf_rne(w - hf);
    } else if (idx < 59392 + NE) {
        int e = idx - 59392;
        atomicAdd(&deg[dst[e]], 1);
    }
}

__global__ void scan_kernel(const int* __restrict__ deg, int* __restrict__ off) {
    __shared__ int part[1024];
    int t = threadIdx.x;
    const int CH = (N_ATOMS + 1023) / 1024; // 20
    int base = t * CH;
    int s = 0;
    for (int i = 0; i < CH; i++) {
        int idx = base + i;
        if (idx < N_ATOMS) s += deg[idx];
    }
    part[t] = s;
    __syncthreads();
    for (int ofs = 1; ofs < 1024; ofs <<= 1) {
        int v = (t >= ofs) ? part[t - ofs] : 0;
        __syncthreads();
        part[t] += v;
        __syncthreads();
    }
    int run = (t == 0) ? 0 : part[t - 1];
    for (int i = 0; i < CH; i++) {
        int idx = base + i;
        if (idx < N_ATOMS) {
            off[idx] = run;
            run += deg[idx];
        }
    }
    if (t == 1023) off[N_ATOMS] = run;
}

// slotOf[e] = CSR slot of edge e; sbkt[slot] = src atom. The mlp kernel writes
// r directly at the slot so the msg gather reads r SEQUENTIALLY.
__global__ void fill_kernel(const int* __restrict__ dst, const int* __restrict__ srcArr,
                            const int* __restrict__ off, int* __restrict__ cursor,
                            int* __restrict__ sbkt, int* __restrict__ slotOf) {
    int e = blockIdx.x * 256 + threadIdx.x;
    if (e >= NE) return;
    int d = dst[e];
    int pos = atomicAdd(&cursor[d], 1);
    int slot = off[d] + pos;
    sbkt[slot] = srcArr[e];
    slotOf[e] = slot;
}

// ---------------- edge MLP via MFMA, 3-term bf16 split (R3 champion, verbatim) ----------------
// block = 128 threads = 2 waves; wave handles 32 edges (2 M-tiles), no barriers
// (wave-private LDS). A: m=lane&15, k=quad*8+j; B: n=lane&15, k=quad*8+j;
// D: n=lane&15, m=quad*4+reg. Writes r at CSR slot so msg reads sequentially.
#define H1S 68   // 64 + 4 pad dwords
#define H2S 132  // 128 + 4 pad
__global__ __launch_bounds__(128) void mlp_mfma_kernel(
    const float* __restrict__ rfv, const float* __restrict__ dij,
    const float* __restrict__ b0, const float* __restrict__ b1, const float* __restrict__ b2,
    const unsigned short* __restrict__ f0h, const unsigned short* __restrict__ f0l,
    const unsigned short* __restrict__ f1h, const unsigned short* __restrict__ f1l,
    const unsigned short* __restrict__ f2h, const unsigned short* __restrict__ f2l,
    const int* __restrict__ slotOf,
    __hip_bfloat16* __restrict__ r) {
    __shared__ float h1s[2][32][H1S];
    __shared__ float h2s[2][32][H2S];
    const int w = threadIdx.x >> 6;
    const int lane = threadIdx.x & 63;
    const int q = lane >> 4;
    const int c = lane & 15;
    const int e0 = (blockIdx.x * 2 + w) * 32;
    float (*h1)[H1S] = h1s[w];
    float (*h2)[H2S] = h2s[w];

    // ---- layer 1: [32,32] x [32,64] -> h1 ----
    {
        bf16x8 ah[2], al[2];
#pragma unroll
        for (int mt = 0; mt < 2; mt++) {
            float v[8];
            const float* p = rfv + (size_t)(e0 + mt * 16 + c) * 32 + q * 8;
            *(float4*)(v)     = *(const float4*)(p);
            *(float4*)(v + 4) = *(const float4*)(p + 4);
            split8(v, ah[mt], al[mt]);
        }
#pragma unroll
        for (int nt = 0; nt < 4; nt++) {
            float bias = b0[nt * 16 + c];
            f32x4 acc[2];
            acc[0] = {bias, bias, bias, bias};
            acc[1] = acc[0];
            bf16x8 bh = *(const bf16x8*)(f0h + (size_t)(nt * 64 + lane) * 8);
            bf16x8 bl = *(const bf16x8*)(f0l + (size_t)(nt * 64 + lane) * 8);
#pragma unroll
            for (int mt = 0; mt < 2; mt++) {
                acc[mt] = MFMA16(al[mt], bh, acc[mt]);
                acc[mt] = MFMA16(ah[mt], bl, acc[mt]);
                acc[mt] = MFMA16(ah[mt], bh, acc[mt]);
            }
#pragma unroll
            for (int mt = 0; mt < 2; mt++)
#pragma unroll
                for (int reg = 0; reg < 4; reg++)
                    h1[mt * 16 + q * 4 + reg][nt * 16 + c] = silu(acc[mt][reg]);
        }
    }

    // ---- layer 2: [32,64] x [64,128] -> h2 ----
    {
        bf16x8 ah[2][2], al[2][2];
#pragma unroll
        for (int mt = 0; mt < 2; mt++)
#pragma unroll
            for (int ks = 0; ks < 2; ks++) {
                float v[8];
                const float* p = &h1[mt * 16 + c][ks * 32 + q * 8];
                *(float4*)(v)     = *(const float4*)(p);
                *(float4*)(v + 4) = *(const float4*)(p + 4);
                split8(v, ah[mt][ks], al[mt][ks]);
            }
#pragma unroll
        for (int nt = 0; nt < 8; nt++) {
            float bias = b1[nt * 16 + c];
            f32x4 acc[2];
            acc[0] = {bias, bias, bias, bias};
            acc[1] = acc[0];
#pragma unroll
            for (int ks = 0; ks < 2; ks++) {
                bf16x8 bh = *(const bf16x8*)(f1h + (size_t)((ks * 8 + nt) * 64 + lane) * 8);
                bf16x8 bl = *(const bf16x8*)(f1l + (size_t)((ks * 8 + nt) * 64 + lane) * 8);
#pragma unroll
                for (int mt = 0; mt < 2; mt++) {
                    acc[mt] = MFMA16(al[mt][ks], bh, acc[mt]);
                    acc[mt] = MFMA16(ah[mt][ks], bl, acc[mt]);
                    acc[mt] = MFMA16(ah[mt][ks], bh, acc[mt]);
                }
            }
#pragma unroll
            for (int mt = 0; mt < 2; mt++)
#pragma unroll
                for (int reg = 0; reg < 4; reg++)
                    h2[mt * 16 + q * 4 + reg][nt * 16 + c] = silu(acc[mt][reg]);
        }
    }

    // ---- layer 3: [32,128] x [128,192] -> r at CSR slot (silu * cutoff, bf16) ----
    {
        bf16x8 ah[2][4], al[2][4];
#pragma unroll
        for (int mt = 0; mt < 2; mt++)
#pragma unroll
            for (int ks = 0; ks < 4; ks++) {
                float v[8];
                const float* p = &h2[mt * 16 + c][ks * 32 + q * 8];
                *(float4*)(v)     = *(const float4*)(p);
                *(float4*)(v + 4) = *(const float4*)(p + 4);
                split8(v, ah[mt][ks], al[mt][ks]);
            }
        float cut[2][4];
        int srow[2][4];
#pragma unroll
        for (int mt = 0; mt < 2; mt++)
#pragma unroll
            for (int reg = 0; reg < 4; reg++) {
                int e = e0 + mt * 16 + q * 4 + reg;
                float d = dij[e];
                cut[mt][reg] = (d < 1.0f) ? 0.5f * (__cosf(PI_F * d) + 1.0f) : 0.0f;
                srow[mt][reg] = slotOf[e];
            }
#pragma unroll
        for (int nt = 0; nt < 12; nt++) {
            float bias = b2[nt * 16 + c];
            f32x4 acc[2];
            acc[0] = {bias, bias, bias, bias};
            acc[1] = acc[0];
#pragma unroll
            for (int ks = 0; ks < 4; ks++) {
                bf16x8 bh = *(const bf16x8*)(f2h + (size_t)((ks * 12 + nt) * 64 + lane) * 8);
                bf16x8 bl = *(const bf16x8*)(f2l + (size_t)((ks * 12 + nt) * 64 + lane) * 8);
#pragma unroll
                for (int mt = 0; mt < 2; mt++) {
                    acc[mt] = MFMA16(al[mt][ks], bh, acc[mt]);
                    acc[mt] = MFMA16(ah[mt][ks], bl, acc[mt]);
                    acc[mt] = MFMA16(ah[mt][ks], bh, acc[mt]);
                }
            }
#pragma unroll
            for (int mt = 0; mt < 2; mt++)
#pragma unroll
                for (int reg = 0; reg < 4; reg++)
                    r[(size_t)srow[mt][reg] * 192 + nt * 16 + c] =
                        __float2bfloat16(silu(acc[mt][reg]) * cut[mt][reg]);
        }
    }
}

// ---------------- fused decompose + lin1 (R3 champion, verbatim) ----------------
// comp rows padded 10 -> 12 floats (48 B, 16B-aligned): gather uses 3x float4.
__global__ __launch_bounds__(256) void lin1_kernel(
    const float* __restrict__ X, const float* __restrict__ wtT,
    float* __restrict__ comp, float* __restrict__ Yb) {
    __shared__ float lds[4][64 * 11];
    int w = threadIdx.x >> 6;
    int l = threadIdx.x & 63;
    int a = blockIdx.x * 4 + w;

    {
        const float* x = X + ((size_t)a * 64 + l) * 9;
        float v[9];
#pragma unroll
        for (int i = 0; i < 9; i++) v[i] = x[i];
        float t2 = 0.f;
#pragma unroll
        for (int i = 0; i < 9; i++) t2 += v[i] * v[i];
        float inv = 1.0f / (t2 + 1.0f);
#pragma unroll
        for (int i = 0; i < 9; i++) v[i] *= inv;
        float iso = (v[0] + v[4] + v[8]) * (1.0f / 3.0f);
        float* o = &lds[w][l * 11];
        o[0] = iso;
        o[1] = 0.5f * (v[1] - v[3]);
        o[2] = 0.5f * (v[2] - v[6]);
        o[3] = 0.5f * (v[5] - v[7]);
        o[4] = v[0] - iso;
        o[5] = 0.5f * (v[1] + v[3]);
        o[6] = 0.5f * (v[2] + v[6]);
        o[7] = v[4] - iso;
        o[8] = 0.5f * (v[5] + v[7]);
        o[9] = v[8] - iso;
    }
    __syncthreads();
    {
        int g = l;
        const float* w0 = wtT;
        const float* w1 = wtT + 4096;
        const float* w2 = wtT + 8192;
        float acc[10];
#pragma unroll
        for (int c = 0; c < 10; c++) acc[c] = 0.f;
        for (int f = 0; f < 64; f++) {
            float wI = w0[f * 64 + g];
            float wA = w1[f * 64 + g];
            float wS = w2[f * 64 + g];
            const float* rf = &lds[w][f * 11];
            acc[0] += wI * rf[0];
            acc[1] += wA * rf[1];
            acc[2] += wA * rf[2];
            acc[3] += wA * rf[3];
#pragma unroll
            for (int c = 4; c < 10; c++) acc[c] += wS * rf[c];
        }
        float* co = comp + ((size_t)a * 64 + g) * 12;
        float4 c0 = {acc[0], acc[1], acc[2], acc[3]};
        float4 c1 = {acc[4], acc[5], acc[6], acc[7]};
        float4 c2 = {acc[8], acc[9], 0.f, 0.f};
        *(float4*)(co)     = c0;
        *(float4*)(co + 4) = c1;
        *(float4*)(co + 8) = c2;
        float* y = Yb + ((size_t)a * 64 + g) * 9;
        y[0] = acc[0] + acc[4];
        y[1] = acc[5] + acc[1];
        y[2] = acc[6] + acc[2];
        y[3] = acc[5] - acc[1];
        y[4] = acc[0] + acc[7];
        y[5] = acc[8] + acc[3];
        y[6] = acc[6] - acc[2];
        y[7] = acc[8] - acc[3];
        y[8] = acc[0] + acc[9];
    }
}

// ---------------- fused message passing + pair + lin2 + epilogue (R3 verbatim) ----------------
// r is slot-ordered: gather reads r streaming; comp is the random gather.
// Depth-1 software pipeline on the gather loop.
__global__ __launch_bounds__(256) void msg_lin2_kernel(
    const int* __restrict__ off, const int* __restrict__ sbkt,
    const __hip_bfloat16* __restrict__ r,
    const float* __restrict__ comp, const float* __restrict__ Yb,
    const float* __restrict__ X, const float* __restrict__ charges,
    const float* __restrict__ wtT, float* __restrict__ out) {
    __shared__ float lds[4][64 * 11];
    int w = threadIdx.x >> 6;
    int l = threadIdx.x & 63;
    int a = blockIdx.x * 4 + w;
    float q = 1.0f + 0.1f * charges[a];

    // ---- message accumulation ----
    float m[10];
#pragma unroll
    for (int c = 0; c < 10; c++) m[c] = 0.f;
    {
        int beg = off[a], end = off[a + 1];
        if (beg < end) {
            __hip_bfloat16 ra, rb, rc;
            float4 c0, c1, c2;
            {
                const __hip_bfloat16* rp = r + (size_t)beg * 192 + l * 3;
                ra = rp[0]; rb = rp[1]; rc = rp[2];
                const float* cp = comp + ((size_t)sbkt[beg] * 64 + l) * 12;
                c0 = *(const float4*)(cp);
                c1 = *(const float4*)(cp + 4);
                c2 = *(const float4*)(cp + 8);
            }
            for (int i = beg + 1; i < end; i++) {
                const __hip_bfloat16* rp = r + (size_t)i * 192 + l * 3;
                __hip_bfloat16 na = rp[0], nb = rp[1], nc = rp[2];
                const float* cp = comp + ((size_t)sbkt[i] * 64 + l) * 12;
                float4 n0 = *(const float4*)(cp);
                float4 n1 = *(const float4*)(cp + 4);
                float4 n2 = *(const float4*)(cp + 8);
                float r0 = __bfloat162float(ra);
                float r1 = __bfloat162float(rb);
                float r2 = __bfloat162float(rc);
                m[0] += r0 * c0.x;
                m[1] += r1 * c0.y;
                m[2] += r1 * c0.z;
                m[3] += r1 * c0.w;
                m[4] += r2 * c1.x;
                m[5] += r2 * c1.y;
                m[6] += r2 * c1.z;
                m[7] += r2 * c1.w;
                m[8] += r2 * c2.x;
                m[9] += r2 * c2.y;
                ra = na; rb = nb; rc = nc;
                c0 = n0; c1 = n1; c2 = n2;
            }
            float r0 = __bfloat162float(ra);
            float r1 = __bfloat162float(rb);
            float r2 = __bfloat162float(rc);
            m[0] += r0 * c0.x;
            m[1] += r1 * c0.y;
            m[2] += r1 * c0.z;
            m[3] += r1 * c0.w;
            m[4] += r2 * c1.x;
            m[5] += r2 * c1.y;
            m[6] += r2 * c1.z;
            m[7] += r2 * c1.w;
            m[8] += r2 * c2.x;
            m[9] += r2 * c2.y;
        }
    }

    // ---- pair term + decompose ----
    {
        float M[9];
        M[0] = m[0] + m[4]; M[1] = m[5] + m[1]; M[2] = m[6] + m[2];
        M[3] = m[5] - m[1]; M[4] = m[0] + m[7]; M[5] = m[8] + m[3];
        M[6] = m[6] - m[2]; M[7] = m[8] - m[3]; M[8] = m[0] + m[9];
        const float* yp = Yb + ((size_t)a * 64 + l) * 9;
        float Y[9];
#pragma unroll
        for (int i = 0; i < 9; i++) Y[i] = yp[i];
        float P[9];
#pragma unroll
        for (int i = 0; i < 3; i++) {
#pragma unroll
            for (int j = 0; j < 3; j++) {
                float s = 0.f;
#pragma unroll
                for (int k = 0; k < 3; k++)
                    s += M[i * 3 + k] * Y[k * 3 + j] + Y[i * 3 + k] * M[k * 3 + j];
                P[i * 3 + j] = q * s;
            }
        }
        float t2 = 0.f;
#pragma unroll
        for (int i = 0; i < 9; i++) t2 += P[i] * P[i];
        float inv = 1.0f / (t2 + 1.0f);
        float iso = (P[0] + P[4] + P[8]) * (1.0f / 3.0f);
        float* o = &lds[w][l * 11];
        o[0] = iso * inv;
        o[1] = 0.5f * (P[1] - P[3]) * inv;
        o[2] = 0.5f * (P[2] - P[6]) * inv;
        o[3] = 0.5f * (P[5] - P[7]) * inv;
        o[4] = (P[0] - iso) * inv;
        o[5] = 0.5f * (P[1] + P[3]) * inv;
        o[6] = 0.5f * (P[2] + P[6]) * inv;
        o[7] = (P[4] - iso) * inv;
        o[8] = 0.5f * (P[5] + P[7]) * inv;
        o[9] = (P[8] - iso) * inv;
    }
    __syncthreads();
    {
        int g = l;
        const float* w3 = wtT + 3 * 4096;
        const float* w4 = wtT + 4 * 4096;
        const float* w5 = wtT + 5 * 4096;
        float acc[10];
#pragma unroll
        for (int c = 0; c < 10; c++) acc[c] = 0.f;
        for (int f = 0; f < 64; f++) {
            float wI = w3[f * 64 + g];
            float wA = w4[f * 64 + g];
            float wS = w5[f * 64 + g];
            const float* rf = &lds[w][f * 11];
            acc[0] += wI * rf[0];
            acc[1] += wA * rf[1];
            acc[2] += wA * rf[2];
            acc[3] += wA * rf[3];
#pragma unroll
            for (int c = 4; c < 10; c++) acc[c] += wS * rf[c];
        }
        float D[9];
        D[0] = acc[0] + acc[4]; D[1] = acc[5] + acc[1]; D[2] = acc[6] + acc[2];
        D[3] = acc[5] - acc[1]; D[4] = acc[0] + acc[7]; D[5] = acc[8] + acc[3];
        D[6] = acc[6] - acc[2]; D[7] = acc[8] - acc[3]; D[8] = acc[0] + acc[9];

        const float* x = X + ((size_t)a * 64 + g) * 9;
        float xv[9];
#pragma unroll
        for (int i = 0; i < 9; i++) xv[i] = x[i];
        float t2 = 0.f;
#pragma unroll
        for (int i = 0; i < 9; i++) t2 += xv[i] * xv[i];
        float invn = 1.0f / (t2 + 1.0f);
#pragma unroll
        for (int i = 0; i < 9; i++) xv[i] *= invn;

        float DD[9];
#pragma unroll
        for (int i = 0; i < 3; i++) {
#pragma unroll
            for (int j = 0; j < 3; j++) {
                float s = 0.f;
#pragma unroll
                for (int k = 0; k < 3; k++) s += D[i * 3 + k] * D[k * 3 + j];
                DD[i * 3 + j] = s;
            }
        }
        float* op = out + ((size_t)a * 64 + g) * 9;
#pragma unroll
        for (int i = 0; i < 9; i++) op[i] = xv[i] + D[i] + q * DD[i];
    }
}

extern "C" void kernel_launch(void* const* d_in, const int* in_sizes, int n_in,
                              void* d_out, int out_size, void* d_ws, size_t ws_size,
                              hipStream_t stream) {
    const float* X       = (const float*)d_in[0];
    const int*   pair    = (const int*)d_in[1];
    const float* dij     = (const float*)d_in[2];
    const float* rfv     = (const float*)d_in[3];
    const float* charges = (const float*)d_in[4];
    const float* W0      = (const float*)d_in[5];
    const float* b0      = (const float*)d_in[6];
    const float* W1      = (const float*)d_in[7];
    const float* b1      = (const float*)d_in[8];
    const float* W2      = (const float*)d_in[9];
    const float* b2      = (const float*)d_in[10];
    const float* Wt      = (const float*)d_in[11];
    float* out = (float*)d_out;

    const int* dst = pair;        // pair_indices[0] (scatter)
    const int* src = pair + NE;   // pair_indices[1] (gather)

    // ---- workspace layout (~190 MB) ----
    char* ws = (char*)d_ws;
    size_t ofs = 0;
    auto alloc = [&](size_t bytes) {
        void* p = ws + ofs;
        ofs += (bytes + 255) & ~(size_t)255;
        return p;
    };
    float* wtT  = (float*)alloc((size_t)6 * 4096 * 4);                 // 96 KB
    unsigned short* f0h = (unsigned short*)alloc(2048 * 2);
    unsigned short* f0l = (unsigned short*)alloc(2048 * 2);
    unsigned short* f1h = (unsigned short*)alloc(8192 * 2);
    unsigned short* f1l = (unsigned short*)alloc(8192 * 2);
    unsigned short* f2h = (unsigned short*)alloc(24576 * 2);
    unsigned short* f2l = (unsigned short*)alloc(24576 * 2);
    float* comp = (float*)alloc((size_t)N_ATOMS * FDIM * 12 * 4);      // 61.4 MB (padded)
    __hip_bfloat16* rbuf = (__hip_bfloat16*)alloc((size_t)NE * 192 * 2); // 122.9 MB
    int* deg    = (int*)alloc((size_t)N_ATOMS * 4);
    int* offarr = (int*)alloc((size_t)(N_ATOMS + 1) * 4);
    int* cursor = (int*)alloc((size_t)N_ATOMS * 4);
    int* sbkt   = (int*)alloc((size_t)NE * 4);
    int* slotOf = (int*)alloc((size_t)NE * 4);
    float* Yb   = out;  // reuse d_out as Y scratch; fully overwritten by msg_lin2

    hipMemsetAsync(deg, 0, (size_t)N_ATOMS * 4, stream);
    hipMemsetAsync(cursor, 0, (size_t)N_ATOMS * 4, stream);

    prep_kernel<<<(59392 + NE + 255) / 256, 256, 0, stream>>>(
        Wt, wtT, W0, W1, W2, f0h, f0l, f1h, f1l, f2h, f2l, dst, deg);
    scan_kernel<<<1, 1024, 0, stream>>>(deg, offarr);
    fill_kernel<<<NE / 256, 256, 0, stream>>>(dst, src, offarr, cursor, sbkt, slotOf);

    mlp_mfma_kernel<<<NE / 64, 128, 0, stream>>>(
        rfv, dij, b0, b1, b2, f0h, f0l, f1h, f1l, f2h, f2l, slotOf, rbuf);

    lin1_kernel<<<N_ATOMS / 4, 256, 0, stream>>>(X, wtT, comp, Yb);

    msg_lin2_kernel<<<N_ATOMS / 4, 256, 0, stream>>>(
        offarr, sbkt, rbuf, comp, Yb, X, charges, wtT, out);
}

// Round 10
// 489.581 us; speedup vs baseline: 2.9063x; 1.1139x over previous
//
#include <hip/hip_runtime.h>
#include <hip/hip_bf16.h>
#include <cmath>

#define N_ATOMS 20000
#define NE      320000
#define FDIM    64
#define NRBF    32
#define PI_F    3.14159265358979323846f

typedef __attribute__((ext_vector_type(8))) short bf16x8;
typedef __attribute__((ext_vector_type(4))) float f32x4;
typedef __attribute__((ext_vector_type(4))) _Float16 f16x4;

#define MFMA16(a, b, c) __builtin_amdgcn_mfma_f32_16x16x32_bf16(a, b, c, 0, 0, 0)

__device__ __forceinline__ float silu(float x) {
    return x / (1.0f + __expf(-x));
}

__device__ __forceinline__ unsigned short f2bf_rne(float x) {
    unsigned u = __float_as_uint(x);
    u += 0x7fffu + ((u >> 16) & 1u);
    return (unsigned short)(u >> 16);
}

// split fp32 -> hi (truncated bf16) + lo (RNE bf16 of residual); hi+lo ~ 2^-17 rel
__device__ __forceinline__ void split8(const float* v, bf16x8& hi, bf16x8& lo) {
#pragma unroll
    for (int j = 0; j < 8; j++) {
        unsigned u = __float_as_uint(v[j]);
        float hf = __uint_as_float(u & 0xffff0000u);
        hi[j] = (short)(u >> 16);
        lo[j] = (short)f2bf_rne(v[j] - hf);
    }
}

// ---------------- merged prep: transpose + wfrag + hist (independent ranges) ----------------
// R9-measured: this regular-dispatch merge is worth ~8.5us vs separate launches.
// (R7: cooperative launch breaks the harness -- never use it here.)
__global__ void prep_kernel(const float* __restrict__ Wt, float* __restrict__ wtT,
                            const float* __restrict__ W0, const float* __restrict__ W1,
                            const float* __restrict__ W2,
                            unsigned short* __restrict__ f0h, unsigned short* __restrict__ f0l,
                            unsigned short* __restrict__ f1h, unsigned short* __restrict__ f1l,
                            unsigned short* __restrict__ f2h, unsigned short* __restrict__ f2l,
                            const int* __restrict__ dst, int* __restrict__ deg) {
    int idx = blockIdx.x * 256 + threadIdx.x;
    if (idx < 24576) {
        // transpose wtT[k][f][g] from Wt[k][g][f]
        int k = idx >> 12;
        int r = idx & 4095;
        int g = r >> 6;
        int f = r & 63;
        wtT[k * 4096 + f * 64 + g] = Wt[idx];
    } else if (idx < 59392) {
        // weight fragment prep: hi/lo bf16 planes, MFMA B-layout
        int t = idx - 24576;
        const float* W;
        unsigned short *fh, *fl;
        int K, NT;
        if (t < 2048)       { W = W0; fh = f0h; fl = f0l;             K = 32;  NT = 4; }
        else if (t < 10240) { W = W1; fh = f1h; fl = f1l; t -= 2048;  K = 64;  NT = 8; }
        else                { W = W2; fh = f2h; fl = f2l; t -= 10240; K = 128; NT = 12; }
        int j = t & 7;
        int lane = (t >> 3) & 63;
        int rest = t >> 9;
        int nt = rest % NT;
        int ks = rest / NT;
        int k = ks * 32 + ((lane >> 4) & 3) * 8 + j;
        int n = nt * 16 + (lane & 15);
        float w = W[n * K + k];
        unsigned u = __float_as_uint(w);
        float hf = __uint_as_float(u & 0xffff0000u);
        fh[t] = (unsigned short)(u >> 16);
        fl[t] = f2bf_rne(w - hf);
    } else if (idx < 59392 + NE) {
        int e = idx - 59392;
        atomicAdd(&deg[dst[e]], 1);
    }
}

__global__ void scan_kernel(const int* __restrict__ deg, int* __restrict__ off) {
    __shared__ int part[1024];
    int t = threadIdx.x;
    const int CH = (N_ATOMS + 1023) / 1024; // 20
    int base = t * CH;
    int s = 0;
    for (int i = 0; i < CH; i++) {
        int idx = base + i;
        if (idx < N_ATOMS) s += deg[idx];
    }
    part[t] = s;
    __syncthreads();
    for (int ofs = 1; ofs < 1024; ofs <<= 1) {
        int v = (t >= ofs) ? part[t - ofs] : 0;
        __syncthreads();
        part[t] += v;
        __syncthreads();
    }
    int run = (t == 0) ? 0 : part[t - 1];
    for (int i = 0; i < CH; i++) {
        int idx = base + i;
        if (idx < N_ATOMS) {
            off[idx] = run;
            run += deg[idx];
        }
    }
    if (t == 1023) off[N_ATOMS] = run;
}

// slotOf[e] = CSR slot of edge e; sbkt[slot] = src atom. The mlp kernel writes
// r directly at the slot so the msg gather reads r SEQUENTIALLY.
__global__ void fill_kernel(const int* __restrict__ dst, const int* __restrict__ srcArr,
                            const int* __restrict__ off, int* __restrict__ cursor,
                            int* __restrict__ sbkt, int* __restrict__ slotOf) {
    int e = blockIdx.x * 256 + threadIdx.x;
    if (e >= NE) return;
    int d = dst[e];
    int pos = atomicAdd(&cursor[d], 1);
    int slot = off[d] + pos;
    sbkt[slot] = srcArr[e];
    slotOf[e] = slot;
}

// ---------------- edge MLP via MFMA, 3-term bf16 split (R3 champion, verbatim) ----------------
// block = 128 threads = 2 waves; wave handles 32 edges (2 M-tiles), no barriers
// (wave-private LDS). A: m=lane&15, k=quad*8+j; B: n=lane&15, k=quad*8+j;
// D: n=lane&15, m=quad*4+reg. Writes r at CSR slot so msg reads sequentially.
#define H1S 68   // 64 + 4 pad dwords
#define H2S 132  // 128 + 4 pad
__global__ __launch_bounds__(128) void mlp_mfma_kernel(
    const float* __restrict__ rfv, const float* __restrict__ dij,
    const float* __restrict__ b0, const float* __restrict__ b1, const float* __restrict__ b2,
    const unsigned short* __restrict__ f0h, const unsigned short* __restrict__ f0l,
    const unsigned short* __restrict__ f1h, const unsigned short* __restrict__ f1l,
    const unsigned short* __restrict__ f2h, const unsigned short* __restrict__ f2l,
    const int* __restrict__ slotOf,
    __hip_bfloat16* __restrict__ r) {
    __shared__ float h1s[2][32][H1S];
    __shared__ float h2s[2][32][H2S];
    const int w = threadIdx.x >> 6;
    const int lane = threadIdx.x & 63;
    const int q = lane >> 4;
    const int c = lane & 15;
    const int e0 = (blockIdx.x * 2 + w) * 32;
    float (*h1)[H1S] = h1s[w];
    float (*h2)[H2S] = h2s[w];

    // ---- layer 1: [32,32] x [32,64] -> h1 ----
    {
        bf16x8 ah[2], al[2];
#pragma unroll
        for (int mt = 0; mt < 2; mt++) {
            float v[8];
            const float* p = rfv + (size_t)(e0 + mt * 16 + c) * 32 + q * 8;
            *(float4*)(v)     = *(const float4*)(p);
            *(float4*)(v + 4) = *(const float4*)(p + 4);
            split8(v, ah[mt], al[mt]);
        }
#pragma unroll
        for (int nt = 0; nt < 4; nt++) {
            float bias = b0[nt * 16 + c];
            f32x4 acc[2];
            acc[0] = {bias, bias, bias, bias};
            acc[1] = acc[0];
            bf16x8 bh = *(const bf16x8*)(f0h + (size_t)(nt * 64 + lane) * 8);
            bf16x8 bl = *(const bf16x8*)(f0l + (size_t)(nt * 64 + lane) * 8);
#pragma unroll
            for (int mt = 0; mt < 2; mt++) {
                acc[mt] = MFMA16(al[mt], bh, acc[mt]);
                acc[mt] = MFMA16(ah[mt], bl, acc[mt]);
                acc[mt] = MFMA16(ah[mt], bh, acc[mt]);
            }
#pragma unroll
            for (int mt = 0; mt < 2; mt++)
#pragma unroll
                for (int reg = 0; reg < 4; reg++)
                    h1[mt * 16 + q * 4 + reg][nt * 16 + c] = silu(acc[mt][reg]);
        }
    }

    // ---- layer 2: [32,64] x [64,128] -> h2 ----
    {
        bf16x8 ah[2][2], al[2][2];
#pragma unroll
        for (int mt = 0; mt < 2; mt++)
#pragma unroll
            for (int ks = 0; ks < 2; ks++) {
                float v[8];
                const float* p = &h1[mt * 16 + c][ks * 32 + q * 8];
                *(float4*)(v)     = *(const float4*)(p);
                *(float4*)(v + 4) = *(const float4*)(p + 4);
                split8(v, ah[mt][ks], al[mt][ks]);
            }
#pragma unroll
        for (int nt = 0; nt < 8; nt++) {
            float bias = b1[nt * 16 + c];
            f32x4 acc[2];
            acc[0] = {bias, bias, bias, bias};
            acc[1] = acc[0];
#pragma unroll
            for (int ks = 0; ks < 2; ks++) {
                bf16x8 bh = *(const bf16x8*)(f1h + (size_t)((ks * 8 + nt) * 64 + lane) * 8);
                bf16x8 bl = *(const bf16x8*)(f1l + (size_t)((ks * 8 + nt) * 64 + lane) * 8);
#pragma unroll
                for (int mt = 0; mt < 2; mt++) {
                    acc[mt] = MFMA16(al[mt][ks], bh, acc[mt]);
                    acc[mt] = MFMA16(ah[mt][ks], bl, acc[mt]);
                    acc[mt] = MFMA16(ah[mt][ks], bh, acc[mt]);
                }
            }
#pragma unroll
            for (int mt = 0; mt < 2; mt++)
#pragma unroll
                for (int reg = 0; reg < 4; reg++)
                    h2[mt * 16 + q * 4 + reg][nt * 16 + c] = silu(acc[mt][reg]);
        }
    }

    // ---- layer 3: [32,128] x [128,192] -> r at CSR slot (silu * cutoff, bf16) ----
    {
        bf16x8 ah[2][4], al[2][4];
#pragma unroll
        for (int mt = 0; mt < 2; mt++)
#pragma unroll
            for (int ks = 0; ks < 4; ks++) {
                float v[8];
                const float* p = &h2[mt * 16 + c][ks * 32 + q * 8];
                *(float4*)(v)     = *(const float4*)(p);
                *(float4*)(v + 4) = *(const float4*)(p + 4);
                split8(v, ah[mt][ks], al[mt][ks]);
            }
        float cut[2][4];
        int srow[2][4];
#pragma unroll
        for (int mt = 0; mt < 2; mt++)
#pragma unroll
            for (int reg = 0; reg < 4; reg++) {
                int e = e0 + mt * 16 + q * 4 + reg;
                float d = dij[e];
                cut[mt][reg] = (d < 1.0f) ? 0.5f * (__cosf(PI_F * d) + 1.0f) : 0.0f;
                srow[mt][reg] = slotOf[e];
            }
#pragma unroll
        for (int nt = 0; nt < 12; nt++) {
            float bias = b2[nt * 16 + c];
            f32x4 acc[2];
            acc[0] = {bias, bias, bias, bias};
            acc[1] = acc[0];
#pragma unroll
            for (int ks = 0; ks < 4; ks++) {
                bf16x8 bh = *(const bf16x8*)(f2h + (size_t)((ks * 12 + nt) * 64 + lane) * 8);
                bf16x8 bl = *(const bf16x8*)(f2l + (size_t)((ks * 12 + nt) * 64 + lane) * 8);
#pragma unroll
                for (int mt = 0; mt < 2; mt++) {
                    acc[mt] = MFMA16(al[mt][ks], bh, acc[mt]);
                    acc[mt] = MFMA16(ah[mt][ks], bl, acc[mt]);
                    acc[mt] = MFMA16(ah[mt][ks], bh, acc[mt]);
                }
            }
#pragma unroll
            for (int mt = 0; mt < 2; mt++)
#pragma unroll
                for (int reg = 0; reg < 4; reg++)
                    r[(size_t)srow[mt][reg] * 192 + nt * 16 + c] =
                        __float2bfloat16(silu(acc[mt][reg]) * cut[mt][reg]);
        }
    }
}

// ---------------- fused decompose + lin1 ----------------
// comp rows are now FP16 (12 halves = 24 B, 8B-aligned): halves the msg gather's
// request volume (983 -> 492 MB). f16 rel-err 2^-11 is 16x finer than the bf16
// error already on the r factor in the same products -> absmax unchanged.
__global__ __launch_bounds__(256) void lin1_kernel(
    const float* __restrict__ X, const float* __restrict__ wtT,
    _Float16* __restrict__ comp, float* __restrict__ Yb) {
    __shared__ float lds[4][64 * 11];
    int w = threadIdx.x >> 6;
    int l = threadIdx.x & 63;
    int a = blockIdx.x * 4 + w;

    {
        const float* x = X + ((size_t)a * 64 + l) * 9;
        float v[9];
#pragma unroll
        for (int i = 0; i < 9; i++) v[i] = x[i];
        float t2 = 0.f;
#pragma unroll
        for (int i = 0; i < 9; i++) t2 += v[i] * v[i];
        float inv = 1.0f / (t2 + 1.0f);
#pragma unroll
        for (int i = 0; i < 9; i++) v[i] *= inv;
        float iso = (v[0] + v[4] + v[8]) * (1.0f / 3.0f);
        float* o = &lds[w][l * 11];
        o[0] = iso;
        o[1] = 0.5f * (v[1] - v[3]);
        o[2] = 0.5f * (v[2] - v[6]);
        o[3] = 0.5f * (v[5] - v[7]);
        o[4] = v[0] - iso;
        o[5] = 0.5f * (v[1] + v[3]);
        o[6] = 0.5f * (v[2] + v[6]);
        o[7] = v[4] - iso;
        o[8] = 0.5f * (v[5] + v[7]);
        o[9] = v[8] - iso;
    }
    __syncthreads();
    {
        int g = l;
        const float* w0 = wtT;
        const float* w1 = wtT + 4096;
        const float* w2 = wtT + 8192;
        float acc[10];
#pragma unroll
        for (int c = 0; c < 10; c++) acc[c] = 0.f;
        for (int f = 0; f < 64; f++) {
            float wI = w0[f * 64 + g];
            float wA = w1[f * 64 + g];
            float wS = w2[f * 64 + g];
            const float* rf = &lds[w][f * 11];
            acc[0] += wI * rf[0];
            acc[1] += wA * rf[1];
            acc[2] += wA * rf[2];
            acc[3] += wA * rf[3];
#pragma unroll
            for (int c = 4; c < 10; c++) acc[c] += wS * rf[c];
        }
        _Float16* co = comp + ((size_t)a * 64 + g) * 12;
        f16x4 c0 = {(_Float16)acc[0], (_Float16)acc[1], (_Float16)acc[2], (_Float16)acc[3]};
        f16x4 c1 = {(_Float16)acc[4], (_Float16)acc[5], (_Float16)acc[6], (_Float16)acc[7]};
        f16x4 c2 = {(_Float16)acc[8], (_Float16)acc[9], (_Float16)0.f, (_Float16)0.f};
        *(f16x4*)(co)     = c0;
        *(f16x4*)(co + 4) = c1;
        *(f16x4*)(co + 8) = c2;
        float* y = Yb + ((size_t)a * 64 + g) * 9;
        y[0] = acc[0] + acc[4];
        y[1] = acc[5] + acc[1];
        y[2] = acc[6] + acc[2];
        y[3] = acc[5] - acc[1];
        y[4] = acc[0] + acc[7];
        y[5] = acc[8] + acc[3];
        y[6] = acc[6] - acc[2];
        y[7] = acc[8] - acc[3];
        y[8] = acc[0] + acc[9];
    }
}

// ---------------- fused message passing + pair + lin2 + epilogue ----------------
// r slot-ordered streaming; comp is the random gather, now FP16 (24 B/lane/edge,
// 3x 8B loads). Depth-1 software pipeline on the gather loop.
__global__ __launch_bounds__(256) void msg_lin2_kernel(
    const int* __restrict__ off, const int* __restrict__ sbkt,
    const __hip_bfloat16* __restrict__ r,
    const _Float16* __restrict__ comp, const float* __restrict__ Yb,
    const float* __restrict__ X, const float* __restrict__ charges,
    const float* __restrict__ wtT, float* __restrict__ out) {
    __shared__ float lds[4][64 * 11];
    int w = threadIdx.x >> 6;
    int l = threadIdx.x & 63;
    int a = blockIdx.x * 4 + w;
    float q = 1.0f + 0.1f * charges[a];

    // ---- message accumulation ----
    float m[10];
#pragma unroll
    for (int c = 0; c < 10; c++) m[c] = 0.f;
    {
        int beg = off[a], end = off[a + 1];
        if (beg < end) {
            __hip_bfloat16 ra, rb, rc;
            f16x4 c0, c1, c2;
            {
                const __hip_bfloat16* rp = r + (size_t)beg * 192 + l * 3;
                ra = rp[0]; rb = rp[1]; rc = rp[2];
                const _Float16* cp = comp + ((size_t)sbkt[beg] * 64 + l) * 12;
                c0 = *(const f16x4*)(cp);
                c1 = *(const f16x4*)(cp + 4);
                c2 = *(const f16x4*)(cp + 8);
            }
            for (int i = beg + 1; i < end; i++) {
                const __hip_bfloat16* rp = r + (size_t)i * 192 + l * 3;
                __hip_bfloat16 na = rp[0], nb = rp[1], nc = rp[2];
                const _Float16* cp = comp + ((size_t)sbkt[i] * 64 + l) * 12;
                f16x4 n0 = *(const f16x4*)(cp);
                f16x4 n1 = *(const f16x4*)(cp + 4);
                f16x4 n2 = *(const f16x4*)(cp + 8);
                float r0 = __bfloat162float(ra);
                float r1 = __bfloat162float(rb);
                float r2 = __bfloat162float(rc);
                m[0] += r0 * (float)c0[0];
                m[1] += r1 * (float)c0[1];
                m[2] += r1 * (float)c0[2];
                m[3] += r1 * (float)c0[3];
                m[4] += r2 * (float)c1[0];
                m[5] += r2 * (float)c1[1];
                m[6] += r2 * (float)c1[2];
                m[7] += r2 * (float)c1[3];
                m[8] += r2 * (float)c2[0];
                m[9] += r2 * (float)c2[1];
                ra = na; rb = nb; rc = nc;
                c0 = n0; c1 = n1; c2 = n2;
            }
            float r0 = __bfloat162float(ra);
            float r1 = __bfloat162float(rb);
            float r2 = __bfloat162float(rc);
            m[0] += r0 * (float)c0[0];
            m[1] += r1 * (float)c0[1];
            m[2] += r1 * (float)c0[2];
            m[3] += r1 * (float)c0[3];
            m[4] += r2 * (float)c1[0];
            m[5] += r2 * (float)c1[1];
            m[6] += r2 * (float)c1[2];
            m[7] += r2 * (float)c1[3];
            m[8] += r2 * (float)c2[0];
            m[9] += r2 * (float)c2[1];
        }
    }

    // ---- pair term + decompose ----
    {
        float M[9];
        M[0] = m[0] + m[4]; M[1] = m[5] + m[1]; M[2] = m[6] + m[2];
        M[3] = m[5] - m[1]; M[4] = m[0] + m[7]; M[5] = m[8] + m[3];
        M[6] = m[6] - m[2]; M[7] = m[8] - m[3]; M[8] = m[0] + m[9];
        const float* yp = Yb + ((size_t)a * 64 + l) * 9;
        float Y[9];
#pragma unroll
        for (int i = 0; i < 9; i++) Y[i] = yp[i];
        float P[9];
#pragma unroll
        for (int i = 0; i < 3; i++) {
#pragma unroll
            for (int j = 0; j < 3; j++) {
                float s = 0.f;
#pragma unroll
                for (int k = 0; k < 3; k++)
                    s += M[i * 3 + k] * Y[k * 3 + j] + Y[i * 3 + k] * M[k * 3 + j];
                P[i * 3 + j] = q * s;
            }
        }
        float t2 = 0.f;
#pragma unroll
        for (int i = 0; i < 9; i++) t2 += P[i] * P[i];
        float inv = 1.0f / (t2 + 1.0f);
        float iso = (P[0] + P[4] + P[8]) * (1.0f / 3.0f);
        float* o = &lds[w][l * 11];
        o[0] = iso * inv;
        o[1] = 0.5f * (P[1] - P[3]) * inv;
        o[2] = 0.5f * (P[2] - P[6]) * inv;
        o[3] = 0.5f * (P[5] - P[7]) * inv;
        o[4] = (P[0] - iso) * inv;
        o[5] = 0.5f * (P[1] + P[3]) * inv;
        o[6] = 0.5f * (P[2] + P[6]) * inv;
        o[7] = (P[4] - iso) * inv;
        o[8] = 0.5f * (P[5] + P[7]) * inv;
        o[9] = (P[8] - iso) * inv;
    }
    __syncthreads();
    {
        int g = l;
        const float* w3 = wtT + 3 * 4096;
        const float* w4 = wtT + 4 * 4096;
        const float* w5 = wtT + 5 * 4096;
        float acc[10];
#pragma unroll
        for (int c = 0; c < 10; c++) acc[c] = 0.f;
        for (int f = 0; f < 64; f++) {
            float wI = w3[f * 64 + g];
            float wA = w4[f * 64 + g];
            float wS = w5[f * 64 + g];
            const float* rf = &lds[w][f * 11];
            acc[0] += wI * rf[0];
            acc[1] += wA * rf[1];
            acc[2] += wA * rf[2];
            acc[3] += wA * rf[3];
#pragma unroll
            for (int c = 4; c < 10; c++) acc[c] += wS * rf[c];
        }
        float D[9];
        D[0] = acc[0] + acc[4]; D[1] = acc[5] + acc[1]; D[2] = acc[6] + acc[2];
        D[3] = acc[5] - acc[1]; D[4] = acc[0] + acc[7]; D[5] = acc[8] + acc[3];
        D[6] = acc[6] - acc[2]; D[7] = acc[8] - acc[3]; D[8] = acc[0] + acc[9];

        const float* x = X + ((size_t)a * 64 + g) * 9;
        float xv[9];
#pragma unroll
        for (int i = 0; i < 9; i++) xv[i] = x[i];
        float t2 = 0.f;
#pragma unroll
        for (int i = 0; i < 9; i++) t2 += xv[i] * xv[i];
        float invn = 1.0f / (t2 + 1.0f);
#pragma unroll
        for (int i = 0; i < 9; i++) xv[i] *= invn;

        float DD[9];
#pragma unroll
        for (int i = 0; i < 3; i++) {
#pragma unroll
            for (int j = 0; j < 3; j++) {
                float s = 0.f;
#pragma unroll
                for (int k = 0; k < 3; k++) s += D[i * 3 + k] * D[k * 3 + j];
                DD[i * 3 + j] = s;
            }
        }
        float* op = out + ((size_t)a * 64 + g) * 9;
#pragma unroll
        for (int i = 0; i < 9; i++) op[i] = xv[i] + D[i] + q * DD[i];
    }
}

extern "C" void kernel_launch(void* const* d_in, const int* in_sizes, int n_in,
                              void* d_out, int out_size, void* d_ws, size_t ws_size,
                              hipStream_t stream) {
    const float* X       = (const float*)d_in[0];
    const int*   pair    = (const int*)d_in[1];
    const float* dij     = (const float*)d_in[2];
    const float* rfv     = (const float*)d_in[3];
    const float* charges = (const float*)d_in[4];
    const float* W0      = (const float*)d_in[5];
    const float* b0      = (const float*)d_in[6];
    const float* W1      = (const float*)d_in[7];
    const float* b1      = (const float*)d_in[8];
    const float* W2      = (const float*)d_in[9];
    const float* b2      = (const float*)d_in[10];
    const float* Wt      = (const float*)d_in[11];
    float* out = (float*)d_out;

    const int* dst = pair;        // pair_indices[0] (scatter)
    const int* src = pair + NE;   // pair_indices[1] (gather)

    // ---- workspace layout (~160 MB) ----
    char* ws = (char*)d_ws;
    size_t ofs = 0;
    auto alloc = [&](size_t bytes) {
        void* p = ws + ofs;
        ofs += (bytes + 255) & ~(size_t)255;
        return p;
    };
    float* wtT  = (float*)alloc((size_t)6 * 4096 * 4);                 // 96 KB
    unsigned short* f0h = (unsigned short*)alloc(2048 * 2);
    unsigned short* f0l = (unsigned short*)alloc(2048 * 2);
    unsigned short* f1h = (unsigned short*)alloc(8192 * 2);
    unsigned short* f1l = (unsigned short*)alloc(8192 * 2);
    unsigned short* f2h = (unsigned short*)alloc(24576 * 2);
    unsigned short* f2l = (unsigned short*)alloc(24576 * 2);
    _Float16* comp = (_Float16*)alloc((size_t)N_ATOMS * FDIM * 12 * 2); // 30.7 MB (f16)
    __hip_bfloat16* rbuf = (__hip_bfloat16*)alloc((size_t)NE * 192 * 2); // 122.9 MB
    int* deg    = (int*)alloc((size_t)N_ATOMS * 4);
    int* offarr = (int*)alloc((size_t)(N_ATOMS + 1) * 4);
    int* cursor = (int*)alloc((size_t)N_ATOMS * 4);
    int* sbkt   = (int*)alloc((size_t)NE * 4);
    int* slotOf = (int*)alloc((size_t)NE * 4);
    float* Yb   = out;  // reuse d_out as Y scratch; fully overwritten by msg_lin2

    hipMemsetAsync(deg, 0, (size_t)N_ATOMS * 4, stream);
    hipMemsetAsync(cursor, 0, (size_t)N_ATOMS * 4, stream);

    prep_kernel<<<(59392 + NE + 255) / 256, 256, 0, stream>>>(
        Wt, wtT, W0, W1, W2, f0h, f0l, f1h, f1l, f2h, f2l, dst, deg);
    scan_kernel<<<1, 1024, 0, stream>>>(deg, offarr);
    fill_kernel<<<NE / 256, 256, 0, stream>>>(dst, src, offarr, cursor, sbkt, slotOf);

    mlp_mfma_kernel<<<NE / 64, 128, 0, stream>>>(
        rfv, dij, b0, b1, b2, f0h, f0l, f1h, f1l, f2h, f2l, slotOf, rbuf);

    lin1_kernel<<<N_ATOMS / 4, 256, 0, stream>>>(X, wtT, comp, Yb);

    msg_lin2_kernel<<<N_ATOMS / 4, 256, 0, stream>>>(
        offarr, sbkt, rbuf, comp, Yb, X, charges, wtT, out);
}

// Round 11
// 460.165 us; speedup vs baseline: 3.0921x; 1.0639x over previous
//
#include <hip/hip_runtime.h>
#include <hip/hip_bf16.h>
#include <cmath>

#define N_ATOMS 20000
#define NE      320000
#define FDIM    64
#define NRBF    32
#define PI_F    3.14159265358979323846f

typedef __attribute__((ext_vector_type(8))) short bf16x8;
typedef __attribute__((ext_vector_type(4))) float f32x4;
typedef __attribute__((ext_vector_type(4))) _Float16 f16x4;

#define MFMA16(a, b, c) __builtin_amdgcn_mfma_f32_16x16x32_bf16(a, b, c, 0, 0, 0)

// silu via fast v_rcp_f32 (~2^-22 rel err) instead of IEEE div (~10 instr).
// Every consumer quantizes harder (hi/lo split 2^-17, bf16 r 2^-8) -> invisible.
// R11: this removes ~half of mlp_mfma's VALU work (192 silus/lane, div was
// the dominant per-silu cost under -O3 without fast-math).
__device__ __forceinline__ float silu(float x) {
    return x * __builtin_amdgcn_rcpf(1.0f + __expf(-x));
}

__device__ __forceinline__ unsigned short f2bf_rne(float x) {
    unsigned u = __float_as_uint(x);
    u += 0x7fffu + ((u >> 16) & 1u);
    return (unsigned short)(u >> 16);
}

// split fp32 -> hi (truncated bf16) + lo (RNE bf16 of residual); hi+lo ~ 2^-17 rel
__device__ __forceinline__ void split8(const float* v, bf16x8& hi, bf16x8& lo) {
#pragma unroll
    for (int j = 0; j < 8; j++) {
        unsigned u = __float_as_uint(v[j]);
        float hf = __uint_as_float(u & 0xffff0000u);
        hi[j] = (short)(u >> 16);
        lo[j] = (short)f2bf_rne(v[j] - hf);
    }
}

// ---------------- merged prep: transpose + wfrag + hist (independent ranges) ----------------
// R9-measured: this regular-dispatch merge is worth ~8.5us vs separate launches.
// (R7: cooperative launch breaks the harness -- never use it here.)
__global__ void prep_kernel(const float* __restrict__ Wt, float* __restrict__ wtT,
                            const float* __restrict__ W0, const float* __restrict__ W1,
                            const float* __restrict__ W2,
                            unsigned short* __restrict__ f0h, unsigned short* __restrict__ f0l,
                            unsigned short* __restrict__ f1h, unsigned short* __restrict__ f1l,
                            unsigned short* __restrict__ f2h, unsigned short* __restrict__ f2l,
                            const int* __restrict__ dst, int* __restrict__ deg) {
    int idx = blockIdx.x * 256 + threadIdx.x;
    if (idx < 24576) {
        // transpose wtT[k][f][g] from Wt[k][g][f]
        int k = idx >> 12;
        int r = idx & 4095;
        int g = r >> 6;
        int f = r & 63;
        wtT[k * 4096 + f * 64 + g] = Wt[idx];
    } else if (idx < 59392) {
        // weight fragment prep: hi/lo bf16 planes, MFMA B-layout
        int t = idx - 24576;
        const float* W;
        unsigned short *fh, *fl;
        int K, NT;
        if (t < 2048)       { W = W0; fh = f0h; fl = f0l;             K = 32;  NT = 4; }
        else if (t < 10240) { W = W1; fh = f1h; fl = f1l; t -= 2048;  K = 64;  NT = 8; }
        else                { W = W2; fh = f2h; fl = f2l; t -= 10240; K = 128; NT = 12; }
        int j = t & 7;
        int lane = (t >> 3) & 63;
        int rest = t >> 9;
        int nt = rest % NT;
        int ks = rest / NT;
        int k = ks * 32 + ((lane >> 4) & 3) * 8 + j;
        int n = nt * 16 + (lane & 15);
        float w = W[n * K + k];
        unsigned u = __float_as_uint(w);
        float hf = __uint_as_float(u & 0xffff0000u);
        fh[t] = (unsigned short)(u >> 16);
        fl[t] = f2bf_rne(w - hf);
    } else if (idx < 59392 + NE) {
        int e = idx - 59392;
        atomicAdd(&deg[dst[e]], 1);
    }
}

__global__ void scan_kernel(const int* __restrict__ deg, int* __restrict__ off) {
    __shared__ int part[1024];
    int t = threadIdx.x;
    const int CH = (N_ATOMS + 1023) / 1024; // 20
    int base = t * CH;
    int s = 0;
    for (int i = 0; i < CH; i++) {
        int idx = base + i;
        if (idx < N_ATOMS) s += deg[idx];
    }
    part[t] = s;
    __syncthreads();
    for (int ofs = 1; ofs < 1024; ofs <<= 1) {
        int v = (t >= ofs) ? part[t - ofs] : 0;
        __syncthreads();
        part[t] += v;
        __syncthreads();
    }
    int run = (t == 0) ? 0 : part[t - 1];
    for (int i = 0; i < CH; i++) {
        int idx = base + i;
        if (idx < N_ATOMS) {
            off[idx] = run;
            run += deg[idx];
        }
    }
    if (t == 1023) off[N_ATOMS] = run;
}

// slotOf[e] = CSR slot of edge e; sbkt[slot] = src atom. The mlp kernel writes
// r directly at the slot so the msg gather reads r SEQUENTIALLY.
__global__ void fill_kernel(const int* __restrict__ dst, const int* __restrict__ srcArr,
                            const int* __restrict__ off, int* __restrict__ cursor,
                            int* __restrict__ sbkt, int* __restrict__ slotOf) {
    int e = blockIdx.x * 256 + threadIdx.x;
    if (e >= NE) return;
    int d = dst[e];
    int pos = atomicAdd(&cursor[d], 1);
    int slot = off[d] + pos;
    sbkt[slot] = srcArr[e];
    slotOf[e] = slot;
}

// ---------------- edge MLP via MFMA, 3-term bf16 split ----------------
// block = 128 threads = 2 waves; wave handles 32 edges (2 M-tiles), no barriers
// (wave-private LDS). A: m=lane&15, k=quad*8+j; B: n=lane&15, k=quad*8+j;
// D: n=lane&15, m=quad*4+reg. Writes r at CSR slot so msg reads sequentially.
#define H1S 68   // 64 + 4 pad dwords
#define H2S 132  // 128 + 4 pad
__global__ __launch_bounds__(128) void mlp_mfma_kernel(
    const float* __restrict__ rfv, const float* __restrict__ dij,
    const float* __restrict__ b0, const float* __restrict__ b1, const float* __restrict__ b2,
    const unsigned short* __restrict__ f0h, const unsigned short* __restrict__ f0l,
    const unsigned short* __restrict__ f1h, const unsigned short* __restrict__ f1l,
    const unsigned short* __restrict__ f2h, const unsigned short* __restrict__ f2l,
    const int* __restrict__ slotOf,
    __hip_bfloat16* __restrict__ r) {
    __shared__ float h1s[2][32][H1S];
    __shared__ float h2s[2][32][H2S];
    const int w = threadIdx.x >> 6;
    const int lane = threadIdx.x & 63;
    const int q = lane >> 4;
    const int c = lane & 15;
    const int e0 = (blockIdx.x * 2 + w) * 32;
    float (*h1)[H1S] = h1s[w];
    float (*h2)[H2S] = h2s[w];

    // ---- layer 1: [32,32] x [32,64] -> h1 ----
    {
        bf16x8 ah[2], al[2];
#pragma unroll
        for (int mt = 0; mt < 2; mt++) {
            float v[8];
            const float* p = rfv + (size_t)(e0 + mt * 16 + c) * 32 + q * 8;
            *(float4*)(v)     = *(const float4*)(p);
            *(float4*)(v + 4) = *(const float4*)(p + 4);
            split8(v, ah[mt], al[mt]);
        }
#pragma unroll
        for (int nt = 0; nt < 4; nt++) {
            float bias = b0[nt * 16 + c];
            f32x4 acc[2];
            acc[0] = {bias, bias, bias, bias};
            acc[1] = acc[0];
            bf16x8 bh = *(const bf16x8*)(f0h + (size_t)(nt * 64 + lane) * 8);
            bf16x8 bl = *(const bf16x8*)(f0l + (size_t)(nt * 64 + lane) * 8);
#pragma unroll
            for (int mt = 0; mt < 2; mt++) {
                acc[mt] = MFMA16(al[mt], bh, acc[mt]);
                acc[mt] = MFMA16(ah[mt], bl, acc[mt]);
                acc[mt] = MFMA16(ah[mt], bh, acc[mt]);
            }
#pragma unroll
            for (int mt = 0; mt < 2; mt++)
#pragma unroll
                for (int reg = 0; reg < 4; reg++)
                    h1[mt * 16 + q * 4 + reg][nt * 16 + c] = silu(acc[mt][reg]);
        }
    }

    // ---- layer 2: [32,64] x [64,128] -> h2 ----
    {
        bf16x8 ah[2][2], al[2][2];
#pragma unroll
        for (int mt = 0; mt < 2; mt++)
#pragma unroll
            for (int ks = 0; ks < 2; ks++) {
                float v[8];
                const float* p = &h1[mt * 16 + c][ks * 32 + q * 8];
                *(float4*)(v)     = *(const float4*)(p);
                *(float4*)(v + 4) = *(const float4*)(p + 4);
                split8(v, ah[mt][ks], al[mt][ks]);
            }
#pragma unroll
        for (int nt = 0; nt < 8; nt++) {
            float bias = b1[nt * 16 + c];
            f32x4 acc[2];
            acc[0] = {bias, bias, bias, bias};
            acc[1] = acc[0];
#pragma unroll
            for (int ks = 0; ks < 2; ks++) {
                bf16x8 bh = *(const bf16x8*)(f1h + (size_t)((ks * 8 + nt) * 64 + lane) * 8);
                bf16x8 bl = *(const bf16x8*)(f1l + (size_t)((ks * 8 + nt) * 64 + lane) * 8);
#pragma unroll
                for (int mt = 0; mt < 2; mt++) {
                    acc[mt] = MFMA16(al[mt][ks], bh, acc[mt]);
                    acc[mt] = MFMA16(ah[mt][ks], bl, acc[mt]);
                    acc[mt] = MFMA16(ah[mt][ks], bh, acc[mt]);
                }
            }
#pragma unroll
            for (int mt = 0; mt < 2; mt++)
#pragma unroll
                for (int reg = 0; reg < 4; reg++)
                    h2[mt * 16 + q * 4 + reg][nt * 16 + c] = silu(acc[mt][reg]);
        }
    }

    // ---- layer 3: [32,128] x [128,192] -> r at CSR slot (silu * cutoff, bf16) ----
    {
        bf16x8 ah[2][4], al[2][4];
#pragma unroll
        for (int mt = 0; mt < 2; mt++)
#pragma unroll
            for (int ks = 0; ks < 4; ks++) {
                float v[8];
                const float* p = &h2[mt * 16 + c][ks * 32 + q * 8];
                *(float4*)(v)     = *(const float4*)(p);
                *(float4*)(v + 4) = *(const float4*)(p + 4);
                split8(v, ah[mt][ks], al[mt][ks]);
            }
        float cut[2][4];
        int srow[2][4];
#pragma unroll
        for (int mt = 0; mt < 2; mt++)
#pragma unroll
            for (int reg = 0; reg < 4; reg++) {
                int e = e0 + mt * 16 + q * 4 + reg;
                float d = dij[e];
                cut[mt][reg] = (d < 1.0f) ? 0.5f * (__cosf(PI_F * d) + 1.0f) : 0.0f;
                srow[mt][reg] = slotOf[e];
            }
#pragma unroll
        for (int nt = 0; nt < 12; nt++) {
            float bias = b2[nt * 16 + c];
            f32x4 acc[2];
            acc[0] = {bias, bias, bias, bias};
            acc[1] = acc[0];
#pragma unroll
            for (int ks = 0; ks < 4; ks++) {
                bf16x8 bh = *(const bf16x8*)(f2h + (size_t)((ks * 12 + nt) * 64 + lane) * 8);
                bf16x8 bl = *(const bf16x8*)(f2l + (size_t)((ks * 12 + nt) * 64 + lane) * 8);
#pragma unroll
                for (int mt = 0; mt < 2; mt++) {
                    acc[mt] = MFMA16(al[mt][ks], bh, acc[mt]);
                    acc[mt] = MFMA16(ah[mt][ks], bl, acc[mt]);
                    acc[mt] = MFMA16(ah[mt][ks], bh, acc[mt]);
                }
            }
#pragma unroll
            for (int mt = 0; mt < 2; mt++)
#pragma unroll
                for (int reg = 0; reg < 4; reg++)
                    r[(size_t)srow[mt][reg] * 192 + nt * 16 + c] =
                        __float2bfloat16(silu(acc[mt][reg]) * cut[mt][reg]);
        }
    }
}

// ---------------- fused decompose + lin1 ----------------
// comp rows FP16 (12 halves = 24 B, 8B-aligned): halves the msg gather's request
// volume. f16 rel-err 2^-11 is 16x finer than the bf16 error already on r.
__global__ __launch_bounds__(256) void lin1_kernel(
    const float* __restrict__ X, const float* __restrict__ wtT,
    _Float16* __restrict__ comp, float* __restrict__ Yb) {
    __shared__ float lds[4][64 * 11];
    int w = threadIdx.x >> 6;
    int l = threadIdx.x & 63;
    int a = blockIdx.x * 4 + w;

    {
        const float* x = X + ((size_t)a * 64 + l) * 9;
        float v[9];
#pragma unroll
        for (int i = 0; i < 9; i++) v[i] = x[i];
        float t2 = 0.f;
#pragma unroll
        for (int i = 0; i < 9; i++) t2 += v[i] * v[i];
        float inv = 1.0f / (t2 + 1.0f);
#pragma unroll
        for (int i = 0; i < 9; i++) v[i] *= inv;
        float iso = (v[0] + v[4] + v[8]) * (1.0f / 3.0f);
        float* o = &lds[w][l * 11];
        o[0] = iso;
        o[1] = 0.5f * (v[1] - v[3]);
        o[2] = 0.5f * (v[2] - v[6]);
        o[3] = 0.5f * (v[5] - v[7]);
        o[4] = v[0] - iso;
        o[5] = 0.5f * (v[1] + v[3]);
        o[6] = 0.5f * (v[2] + v[6]);
        o[7] = v[4] - iso;
        o[8] = 0.5f * (v[5] + v[7]);
        o[9] = v[8] - iso;
    }
    __syncthreads();
    {
        int g = l;
        const float* w0 = wtT;
        const float* w1 = wtT + 4096;
        const float* w2 = wtT + 8192;
        float acc[10];
#pragma unroll
        for (int c = 0; c < 10; c++) acc[c] = 0.f;
        for (int f = 0; f < 64; f++) {
            float wI = w0[f * 64 + g];
            float wA = w1[f * 64 + g];
            float wS = w2[f * 64 + g];
            const float* rf = &lds[w][f * 11];
            acc[0] += wI * rf[0];
            acc[1] += wA * rf[1];
            acc[2] += wA * rf[2];
            acc[3] += wA * rf[3];
#pragma unroll
            for (int c = 4; c < 10; c++) acc[c] += wS * rf[c];
        }
        _Float16* co = comp + ((size_t)a * 64 + g) * 12;
        f16x4 c0 = {(_Float16)acc[0], (_Float16)acc[1], (_Float16)acc[2], (_Float16)acc[3]};
        f16x4 c1 = {(_Float16)acc[4], (_Float16)acc[5], (_Float16)acc[6], (_Float16)acc[7]};
        f16x4 c2 = {(_Float16)acc[8], (_Float16)acc[9], (_Float16)0.f, (_Float16)0.f};
        *(f16x4*)(co)     = c0;
        *(f16x4*)(co + 4) = c1;
        *(f16x4*)(co + 8) = c2;
        float* y = Yb + ((size_t)a * 64 + g) * 9;
        y[0] = acc[0] + acc[4];
        y[1] = acc[5] + acc[1];
        y[2] = acc[6] + acc[2];
        y[3] = acc[5] - acc[1];
        y[4] = acc[0] + acc[7];
        y[5] = acc[8] + acc[3];
        y[6] = acc[6] - acc[2];
        y[7] = acc[8] - acc[3];
        y[8] = acc[0] + acc[9];
    }
}

// ---------------- fused message passing + pair + lin2 + epilogue ----------------
// r slot-ordered streaming; comp is the random gather (FP16, 24 B/lane/edge,
// 3x 8B loads). Depth-1 software pipeline on the gather loop.
__global__ __launch_bounds__(256) void msg_lin2_kernel(
    const int* __restrict__ off, const int* __restrict__ sbkt,
    const __hip_bfloat16* __restrict__ r,
    const _Float16* __restrict__ comp, const float* __restrict__ Yb,
    const float* __restrict__ X, const float* __restrict__ charges,
    const float* __restrict__ wtT, float* __restrict__ out) {
    __shared__ float lds[4][64 * 11];
    int w = threadIdx.x >> 6;
    int l = threadIdx.x & 63;
    int a = blockIdx.x * 4 + w;
    float q = 1.0f + 0.1f * charges[a];

    // ---- message accumulation ----
    float m[10];
#pragma unroll
    for (int c = 0; c < 10; c++) m[c] = 0.f;
    {
        int beg = off[a], end = off[a + 1];
        if (beg < end) {
            __hip_bfloat16 ra, rb, rc;
            f16x4 c0, c1, c2;
            {
                const __hip_bfloat16* rp = r + (size_t)beg * 192 + l * 3;
                ra = rp[0]; rb = rp[1]; rc = rp[2];
                const _Float16* cp = comp + ((size_t)sbkt[beg] * 64 + l) * 12;
                c0 = *(const f16x4*)(cp);
                c1 = *(const f16x4*)(cp + 4);
                c2 = *(const f16x4*)(cp + 8);
            }
            for (int i = beg + 1; i < end; i++) {
                const __hip_bfloat16* rp = r + (size_t)i * 192 + l * 3;
                __hip_bfloat16 na = rp[0], nb = rp[1], nc = rp[2];
                const _Float16* cp = comp + ((size_t)sbkt[i] * 64 + l) * 12;
                f16x4 n0 = *(const f16x4*)(cp);
                f16x4 n1 = *(const f16x4*)(cp + 4);
                f16x4 n2 = *(const f16x4*)(cp + 8);
                float r0 = __bfloat162float(ra);
                float r1 = __bfloat162float(rb);
                float r2 = __bfloat162float(rc);
                m[0] += r0 * (float)c0[0];
                m[1] += r1 * (float)c0[1];
                m[2] += r1 * (float)c0[2];
                m[3] += r1 * (float)c0[3];
                m[4] += r2 * (float)c1[0];
                m[5] += r2 * (float)c1[1];
                m[6] += r2 * (float)c1[2];
                m[7] += r2 * (float)c1[3];
                m[8] += r2 * (float)c2[0];
                m[9] += r2 * (float)c2[1];
                ra = na; rb = nb; rc = nc;
                c0 = n0; c1 = n1; c2 = n2;
            }
            float r0 = __bfloat162float(ra);
            float r1 = __bfloat162float(rb);
            float r2 = __bfloat162float(rc);
            m[0] += r0 * (float)c0[0];
            m[1] += r1 * (float)c0[1];
            m[2] += r1 * (float)c0[2];
            m[3] += r1 * (float)c0[3];
            m[4] += r2 * (float)c1[0];
            m[5] += r2 * (float)c1[1];
            m[6] += r2 * (float)c1[2];
            m[7] += r2 * (float)c1[3];
            m[8] += r2 * (float)c2[0];
            m[9] += r2 * (float)c2[1];
        }
    }

    // ---- pair term + decompose ----
    {
        float M[9];
        M[0] = m[0] + m[4]; M[1] = m[5] + m[1]; M[2] = m[6] + m[2];
        M[3] = m[5] - m[1]; M[4] = m[0] + m[7]; M[5] = m[8] + m[3];
        M[6] = m[6] - m[2]; M[7] = m[8] - m[3]; M[8] = m[0] + m[9];
        const float* yp = Yb + ((size_t)a * 64 + l) * 9;
        float Y[9];
#pragma unroll
        for (int i = 0; i < 9; i++) Y[i] = yp[i];
        float P[9];
#pragma unroll
        for (int i = 0; i < 3; i++) {
#pragma unroll
            for (int j = 0; j < 3; j++) {
                float s = 0.f;
#pragma unroll
                for (int k = 0; k < 3; k++)
                    s += M[i * 3 + k] * Y[k * 3 + j] + Y[i * 3 + k] * M[k * 3 + j];
                P[i * 3 + j] = q * s;
            }
        }
        float t2 = 0.f;
#pragma unroll
        for (int i = 0; i < 9; i++) t2 += P[i] * P[i];
        float inv = 1.0f / (t2 + 1.0f);
        float iso = (P[0] + P[4] + P[8]) * (1.0f / 3.0f);
        float* o = &lds[w][l * 11];
        o[0] = iso * inv;
        o[1] = 0.5f * (P[1] - P[3]) * inv;
        o[2] = 0.5f * (P[2] - P[6]) * inv;
        o[3] = 0.5f * (P[5] - P[7]) * inv;
        o[4] = (P[0] - iso) * inv;
        o[5] = 0.5f * (P[1] + P[3]) * inv;
        o[6] = 0.5f * (P[2] + P[6]) * inv;
        o[7] = (P[4] - iso) * inv;
        o[8] = 0.5f * (P[5] + P[7]) * inv;
        o[9] = (P[8] - iso) * inv;
    }
    __syncthreads();
    {
        int g = l;
        const float* w3 = wtT + 3 * 4096;
        const float* w4 = wtT + 4 * 4096;
        const float* w5 = wtT + 5 * 4096;
        float acc[10];
#pragma unroll
        for (int c = 0; c < 10; c++) acc[c] = 0.f;
        for (int f = 0; f < 64; f++) {
            float wI = w3[f * 64 + g];
            float wA = w4[f * 64 + g];
            float wS = w5[f * 64 + g];
            const float* rf = &lds[w][f * 11];
            acc[0] += wI * rf[0];
            acc[1] += wA * rf[1];
            acc[2] += wA * rf[2];
            acc[3] += wA * rf[3];
#pragma unroll
            for (int c = 4; c < 10; c++) acc[c] += wS * rf[c];
        }
        float D[9];
        D[0] = acc[0] + acc[4]; D[1] = acc[5] + acc[1]; D[2] = acc[6] + acc[2];
        D[3] = acc[5] - acc[1]; D[4] = acc[0] + acc[7]; D[5] = acc[8] + acc[3];
        D[6] = acc[6] - acc[2]; D[7] = acc[8] - acc[3]; D[8] = acc[0] + acc[9];

        const float* x = X + ((size_t)a * 64 + g) * 9;
        float xv[9];
#pragma unroll
        for (int i = 0; i < 9; i++) xv[i] = x[i];
        float t2 = 0.f;
#pragma unroll
        for (int i = 0; i < 9; i++) t2 += xv[i] * xv[i];
        float invn = 1.0f / (t2 + 1.0f);
#pragma unroll
        for (int i = 0; i < 9; i++) xv[i] *= invn;

        float DD[9];
#pragma unroll
        for (int i = 0; i < 3; i++) {
#pragma unroll
            for (int j = 0; j < 3; j++) {
                float s = 0.f;
#pragma unroll
                for (int k = 0; k < 3; k++) s += D[i * 3 + k] * D[k * 3 + j];
                DD[i * 3 + j] = s;
            }
        }
        float* op = out + ((size_t)a * 64 + g) * 9;
#pragma unroll
        for (int i = 0; i < 9; i++) op[i] = xv[i] + D[i] + q * DD[i];
    }
}

extern "C" void kernel_launch(void* const* d_in, const int* in_sizes, int n_in,
                              void* d_out, int out_size, void* d_ws, size_t ws_size,
                              hipStream_t stream) {
    const float* X       = (const float*)d_in[0];
    const int*   pair    = (const int*)d_in[1];
    const float* dij     = (const float*)d_in[2];
    const float* rfv     = (const float*)d_in[3];
    const float* charges = (const float*)d_in[4];
    const float* W0      = (const float*)d_in[5];
    const float* b0      = (const float*)d_in[6];
    const float* W1      = (const float*)d_in[7];
    const float* b1      = (const float*)d_in[8];
    const float* W2      = (const float*)d_in[9];
    const float* b2      = (const float*)d_in[10];
    const float* Wt      = (const float*)d_in[11];
    float* out = (float*)d_out;

    const int* dst = pair;        // pair_indices[0] (scatter)
    const int* src = pair + NE;   // pair_indices[1] (gather)

    // ---- workspace layout (~160 MB) ----
    char* ws = (char*)d_ws;
    size_t ofs = 0;
    auto alloc = [&](size_t bytes) {
        void* p = ws + ofs;
        ofs += (bytes + 255) & ~(size_t)255;
        return p;
    };
    float* wtT  = (float*)alloc((size_t)6 * 4096 * 4);                 // 96 KB
    unsigned short* f0h = (unsigned short*)alloc(2048 * 2);
    unsigned short* f0l = (unsigned short*)alloc(2048 * 2);
    unsigned short* f1h = (unsigned short*)alloc(8192 * 2);
    unsigned short* f1l = (unsigned short*)alloc(8192 * 2);
    unsigned short* f2h = (unsigned short*)alloc(24576 * 2);
    unsigned short* f2l = (unsigned short*)alloc(24576 * 2);
    _Float16* comp = (_Float16*)alloc((size_t)N_ATOMS * FDIM * 12 * 2); // 30.7 MB (f16)
    __hip_bfloat16* rbuf = (__hip_bfloat16*)alloc((size_t)NE * 192 * 2); // 122.9 MB
    int* deg    = (int*)alloc((size_t)N_ATOMS * 4);
    int* offarr = (int*)alloc((size_t)(N_ATOMS + 1) * 4);
    int* cursor = (int*)alloc((size_t)N_ATOMS * 4);
    int* sbkt   = (int*)alloc((size_t)NE * 4);
    int* slotOf = (int*)alloc((size_t)NE * 4);
    float* Yb   = out;  // reuse d_out as Y scratch; fully overwritten by msg_lin2

    hipMemsetAsync(deg, 0, (size_t)N_ATOMS * 4, stream);
    hipMemsetAsync(cursor, 0, (size_t)N_ATOMS * 4, stream);

    prep_kernel<<<(59392 + NE + 255) / 256, 256, 0, stream>>>(
        Wt, wtT, W0, W1, W2, f0h, f0l, f1h, f1l, f2h, f2l, dst, deg);
    scan_kernel<<<1, 1024, 0, stream>>>(deg, offarr);
    fill_kernel<<<NE / 256, 256, 0, stream>>>(dst, src, offarr, cursor, sbkt, slotOf);

    mlp_mfma_kernel<<<NE / 64, 128, 0, stream>>>(
        rfv, dij, b0, b1, b2, f0h, f0l, f1h, f1l, f2h, f2l, slotOf, rbuf);

    lin1_kernel<<<N_ATOMS / 4, 256, 0, stream>>>(X, wtT, comp, Yb);

    msg_lin2_kernel<<<N_ATOMS / 4, 256, 0, stream>>>(
        offarr, sbkt, rbuf, comp, Yb, X, charges, wtT, out);
}